// Round 1
// baseline (1366.014 us; speedup 1.0000x reference)
//
#include <hip/hip_runtime.h>
#include <math.h>

#define H2C 128   // H*C
#define CDIM 64

static __device__ __forceinline__ float wred64(float x) {
#pragma unroll
  for (int off = 32; off; off >>= 1) x += __shfl_xor(x, off, 64);
  return x;
}

// ---------------- layer-1 vocab tables: embW = emb @ W1, asv/adv per vocab ----
__global__ void k_embw(const float* __restrict__ emb, const float* __restrict__ W1,
                       const float* __restrict__ a_src, const float* __restrict__ a_dst,
                       float* __restrict__ embW, float* __restrict__ asv, float* __restrict__ adv)
{
  int v = blockIdx.x;
  int j = threadIdx.x;           // 0..127 (2 waves: wave0 = head0, wave1 = head1)
  const float* er = emb + v * CDIM;
  float acc = 0.f;
#pragma unroll
  for (int k = 0; k < CDIM; ++k) acc += er[k] * W1[k * H2C + j];
  embW[v * H2C + j] = acc;
  float ps = wred64(acc * a_src[j]);
  float pd = wred64(acc * a_dst[j]);
  if ((j & 63) == 0) {
    int h = j >> 6;
    asv[v * 2 + h] = ps;
    adv[v * 2 + h] = pd;
  }
}

// ---------------- CSR build --------------------------------------------------
__global__ void k_deg(const int* __restrict__ ei, int* __restrict__ deg, int E, int N)
{
  int e = blockIdx.x * blockDim.x + threadIdx.x;
  if (e >= E + N) return;
  int d = (e < E) ? ei[E + e] : (e - E);
  atomicAdd(&deg[d], 1);
}

__global__ void k_scan_a(const int* __restrict__ deg, int* __restrict__ rowptr,
                         int* __restrict__ partials, int n)
{
  __shared__ int sh[256];
  int t = threadIdx.x;
  int base = blockIdx.x * 1024 + t * 4;
  int v0 = 0, v1 = 0, v2 = 0, v3 = 0;
  if (base + 0 < n) v0 = deg[base + 0];
  if (base + 1 < n) v1 = deg[base + 1];
  if (base + 2 < n) v2 = deg[base + 2];
  if (base + 3 < n) v3 = deg[base + 3];
  int lsum = v0 + v1 + v2 + v3;
  sh[t] = lsum;
  __syncthreads();
  for (int offc = 1; offc < 256; offc <<= 1) {
    int x = (t >= offc) ? sh[t - offc] : 0;
    __syncthreads();
    sh[t] += x;
    __syncthreads();
  }
  int run = sh[t] - lsum;
  if (t == 255) partials[blockIdx.x] = sh[255];
  if (base + 0 < n) rowptr[base + 0] = run; run += v0;
  if (base + 1 < n) rowptr[base + 1] = run; run += v1;
  if (base + 2 < n) rowptr[base + 2] = run; run += v2;
  if (base + 3 < n) rowptr[base + 3] = run;
}

__global__ void k_scan_b(int* __restrict__ partials, int nb)
{
  __shared__ int sh[512];
  int t = threadIdx.x;
  int orig = (t < nb) ? partials[t] : 0;
  sh[t] = orig;
  __syncthreads();
  for (int offc = 1; offc < 512; offc <<= 1) {
    int x = (t >= offc) ? sh[t - offc] : 0;
    __syncthreads();
    sh[t] += x;
    __syncthreads();
  }
  if (t < nb) partials[t] = sh[t] - orig;   // exclusive block offsets
}

__global__ void k_scan_c(int* __restrict__ rowptr, int* __restrict__ cursor,
                         const int* __restrict__ partials, int n, int total)
{
  int i = blockIdx.x * blockDim.x + threadIdx.x;
  if (i == 0) rowptr[n] = total;
  if (i >= n) return;
  int r = rowptr[i] + partials[i >> 10];
  rowptr[i] = r;
  cursor[i] = r;
}

__global__ void k_scatter(const int* __restrict__ ei, int* __restrict__ cursor,
                          int* __restrict__ col, int E, int N)
{
  int e = blockIdx.x * blockDim.x + threadIdx.x;
  if (e >= E + N) return;
  int s, d;
  if (e < E) { s = ei[e]; d = ei[E + e]; } else { s = e - E; d = s; }
  int p = atomicAdd(&cursor[d], 1);
  col[p] = s;
}

// ---------------- GAT aggregation, layer 1 (vocab-table values) --------------
__global__ void k_agg1(const int* __restrict__ rowptr, const int* __restrict__ col,
                       const int* __restrict__ xv, const float* __restrict__ embW,
                       const float* __restrict__ asv, const float* __restrict__ adv,
                       const float* __restrict__ b1, float* __restrict__ out, int N)
{
  int wid = (blockIdx.x * blockDim.x + threadIdx.x) >> 6;
  if (wid >= N) return;
  int lane = threadIdx.x & 63;
  int start = rowptr[wid], end = rowptr[wid + 1];
  int vd = xv[wid];
  float ad0 = adv[vd * 2], ad1 = adv[vd * 2 + 1];
  float m0 = -INFINITY, m1 = -INFINITY, s0 = 0.f, s1 = 0.f, a0 = 0.f, a1 = 0.f;
  for (int p = start; p < end; ++p) {
    int s = col[p];
    int vs = xv[s];
    float e0 = asv[vs * 2]     + ad0; e0 = e0 >= 0.f ? e0 : 0.2f * e0;
    float e1 = asv[vs * 2 + 1] + ad1; e1 = e1 >= 0.f ? e1 : 0.2f * e1;
    float v0 = embW[vs * H2C + lane];
    float v1 = embW[vs * H2C + 64 + lane];
    float nm0 = fmaxf(m0, e0), nm1 = fmaxf(m1, e1);
    float sc0 = __expf(m0 - nm0), sc1 = __expf(m1 - nm1);
    float p0 = __expf(e0 - nm0),  p1 = __expf(e1 - nm1);
    s0 = s0 * sc0 + p0;           s1 = s1 * sc1 + p1;
    a0 = a0 * sc0 + p0 * v0;      a1 = a1 * sc1 + p1 * v1;
    m0 = nm0; m1 = nm1;
  }
  out[(size_t)wid * H2C + lane]      = a0 / (s0 + 1e-16f) + b1[lane];
  out[(size_t)wid * H2C + 64 + lane] = a1 / (s1 + 1e-16f) + b1[64 + lane];
}

// ---------------- LN + GELU + @W2 + alpha dots -------------------------------
__global__ void __launch_bounds__(256)
k_mid(const float* __restrict__ in, const float* __restrict__ W2,
      const float* __restrict__ lng, const float* __restrict__ lnb,
      const float* __restrict__ as2w, const float* __restrict__ ad2w,
      float* __restrict__ h2, float* __restrict__ as2, float* __restrict__ ad2, int N)
{
  __shared__ float w2s[H2C * H2C];
  for (int i = threadIdx.x; i < H2C * H2C; i += 256) w2s[i] = W2[i];
  __syncthreads();
  int lane = threadIdx.x & 63;
  int w = threadIdx.x >> 6;
  int step = gridDim.x * 4;
  float g0c = lng[lane], g1c = lng[64 + lane], b0c = lnb[lane], b1c = lnb[64 + lane];
  float as0c = as2w[lane], as1c = as2w[64 + lane];
  float ad0c = ad2w[lane], ad1c = ad2w[64 + lane];
  for (int node = blockIdx.x * 4 + w; node < N; node += step) {
    float x0 = in[(size_t)node * H2C + lane];
    float x1 = in[(size_t)node * H2C + 64 + lane];
    float mean = wred64(x0 + x1) * (1.f / 128.f);
    float var  = wred64(x0 * x0 + x1 * x1) * (1.f / 128.f) - mean * mean;
    float rstd = rsqrtf(var + 1e-5f);
    float v0 = (x0 - mean) * rstd * g0c + b0c;
    float v1 = (x1 - mean) * rstd * g1c + b1c;
    v0 = 0.5f * v0 * (1.f + erff(v0 * 0.70710678118654752f));
    v1 = 0.5f * v1 * (1.f + erff(v1 * 0.70710678118654752f));
    float o0 = 0.f, o1 = 0.f;
    for (int k = 0; k < 64; ++k) {
      float vk = __shfl(v0, k, 64);
      o0 += vk * w2s[k * H2C + lane];
      o1 += vk * w2s[k * H2C + 64 + lane];
    }
    for (int k = 0; k < 64; ++k) {
      float vk = __shfl(v1, k, 64);
      o0 += vk * w2s[(64 + k) * H2C + lane];
      o1 += vk * w2s[(64 + k) * H2C + 64 + lane];
    }
    h2[(size_t)node * H2C + lane]      = o0;
    h2[(size_t)node * H2C + 64 + lane] = o1;
    float ps0 = wred64(o0 * as0c);
    float ps1 = wred64(o1 * as1c);
    float pd0 = wred64(o0 * ad0c);
    float pd1 = wred64(o1 * ad1c);
    if (lane == 0) {
      as2[node * 2] = ps0; as2[node * 2 + 1] = ps1;
      ad2[node * 2] = pd0; ad2[node * 2 + 1] = pd1;
    }
  }
}

// ---------------- GAT aggregation, layer 2 (per-node values) -----------------
__global__ void k_agg2(const int* __restrict__ rowptr, const int* __restrict__ col,
                       const float* __restrict__ h2,
                       const float* __restrict__ as2, const float* __restrict__ ad2,
                       const float* __restrict__ b2, float* __restrict__ out, int N)
{
  int wid = (blockIdx.x * blockDim.x + threadIdx.x) >> 6;
  if (wid >= N) return;
  int lane = threadIdx.x & 63;
  int start = rowptr[wid], end = rowptr[wid + 1];
  float ad0 = ad2[wid * 2], ad1 = ad2[wid * 2 + 1];
  float m0 = -INFINITY, m1 = -INFINITY, s0 = 0.f, s1 = 0.f, a0 = 0.f, a1 = 0.f;
  for (int p = start; p < end; ++p) {
    int s = col[p];
    float e0 = as2[s * 2]     + ad0; e0 = e0 >= 0.f ? e0 : 0.2f * e0;
    float e1 = as2[s * 2 + 1] + ad1; e1 = e1 >= 0.f ? e1 : 0.2f * e1;
    float v0 = h2[(size_t)s * H2C + lane];
    float v1 = h2[(size_t)s * H2C + 64 + lane];
    float nm0 = fmaxf(m0, e0), nm1 = fmaxf(m1, e1);
    float sc0 = __expf(m0 - nm0), sc1 = __expf(m1 - nm1);
    float p0 = __expf(e0 - nm0),  p1 = __expf(e1 - nm1);
    s0 = s0 * sc0 + p0;           s1 = s1 * sc1 + p1;
    a0 = a0 * sc0 + p0 * v0;      a1 = a1 * sc1 + p1 * v1;
    m0 = nm0; m1 = nm1;
  }
  out[(size_t)wid * H2C + lane]      = a0 / (s0 + 1e-16f) + b2[lane];
  out[(size_t)wid * H2C + 64 + lane] = a1 / (s1 + 1e-16f) + b2[64 + lane];
}

// ---------------- final projection @Wp + bp ----------------------------------
__global__ void __launch_bounds__(256)
k_final(const float* __restrict__ in, const float* __restrict__ Wp,
        const float* __restrict__ bp, float* __restrict__ outh, int N)
{
  __shared__ float wps[H2C * CDIM];
  for (int i = threadIdx.x; i < H2C * CDIM; i += 256) wps[i] = Wp[i];
  __syncthreads();
  int lane = threadIdx.x & 63;
  int w = threadIdx.x >> 6;
  int step = gridDim.x * 4;
  float bpc = bp[lane];
  for (int node = blockIdx.x * 4 + w; node < N; node += step) {
    float x0 = in[(size_t)node * H2C + lane];
    float x1 = in[(size_t)node * H2C + 64 + lane];
    float o = 0.f;
    for (int k = 0; k < 64; ++k) {
      float vk = __shfl(x0, k, 64);
      o += vk * wps[k * CDIM + lane];
    }
    for (int k = 0; k < 64; ++k) {
      float vk = __shfl(x1, k, 64);
      o += vk * wps[(64 + k) * CDIM + lane];
    }
    outh[(size_t)node * CDIM + lane] = o + bpc;
  }
}

// ---------------- graph mean pool (batch_idx is sorted) ----------------------
__global__ void k_pool(const float* __restrict__ h3, const int* __restrict__ bidx,
                       float* __restrict__ z, int N)
{
  int g = blockIdx.x;
  int lane = threadIdx.x;   // 64 threads
  int lo = 0, hi = N;
  while (lo < hi) { int mid = (lo + hi) >> 1; if (bidx[mid] < g) lo = mid + 1; else hi = mid; }
  int s0 = lo;
  hi = N;
  while (lo < hi) { int mid = (lo + hi) >> 1; if (bidx[mid] < g + 1) lo = mid + 1; else hi = mid; }
  int s1 = lo;
  float sum = 0.f;
  for (int i = s0; i < s1; ++i) sum += h3[(size_t)i * CDIM + lane];
  z[g * CDIM + lane] = sum / fmaxf((float)(s1 - s0), 1.f);
}

extern "C" void kernel_launch(void* const* d_in, const int* in_sizes, int n_in,
                              void* d_out, int out_size, void* d_ws, size_t ws_size,
                              hipStream_t stream)
{
  const int*   xv   = (const int*)d_in[0];
  const int*   ei   = (const int*)d_in[1];
  const int*   bidx = (const int*)d_in[2];
  const float* emb  = (const float*)d_in[3];
  const float* W1   = (const float*)d_in[4];
  const float* as1  = (const float*)d_in[5];
  const float* ad1  = (const float*)d_in[6];
  const float* b1   = (const float*)d_in[7];
  const float* lng  = (const float*)d_in[8];
  const float* lnb  = (const float*)d_in[9];
  const float* W2   = (const float*)d_in[10];
  const float* as2w = (const float*)d_in[11];
  const float* ad2w = (const float*)d_in[12];
  const float* b2   = (const float*)d_in[13];
  const float* Wp   = (const float*)d_in[14];
  const float* bp   = (const float*)d_in[15];

  const int N   = in_sizes[2];
  const int E   = in_sizes[1] / 2;
  const int V   = in_sizes[3] / CDIM;
  const int NG  = (out_size - N * CDIM) / CDIM;
  const int TOT = E + N;

  size_t off = 0;
  auto alloc = [&](size_t bytes) -> void* {
    void* p = (char*)d_ws + off;
    off += (bytes + 255) & ~(size_t)255;
    return p;
  };
  float* embW   = (float*)alloc((size_t)V * H2C * 4);
  float* asv    = (float*)alloc((size_t)V * 2 * 4);
  float* adv    = (float*)alloc((size_t)V * 2 * 4);
  float* buf1   = (float*)alloc((size_t)N * H2C * 4);   // out1, later reused as out2
  float* h2     = (float*)alloc((size_t)N * H2C * 4);
  float* as2    = (float*)alloc((size_t)N * 2 * 4);
  float* ad2    = (float*)alloc((size_t)N * 2 * 4);
  int*   deg    = (int*)alloc((size_t)N * 4);
  int*   rowptr = (int*)alloc(((size_t)N + 1) * 4);
  int*   cursor = (int*)alloc((size_t)N * 4);
  int*   col    = (int*)alloc((size_t)TOT * 4);
  int*   partials = (int*)alloc(512 * 4);
  (void)ws_size; (void)n_in;

  hipMemsetAsync(deg, 0, (size_t)N * 4, stream);
  k_embw<<<V, 128, 0, stream>>>(emb, W1, as1, ad1, embW, asv, adv);
  int nbE = (TOT + 255) / 256;
  k_deg<<<nbE, 256, 0, stream>>>(ei, deg, E, N);
  int nbS = (N + 1023) / 1024;
  k_scan_a<<<nbS, 256, 0, stream>>>(deg, rowptr, partials, N);
  k_scan_b<<<1, 512, 0, stream>>>(partials, nbS);
  k_scan_c<<<(N + 255) / 256, 256, 0, stream>>>(rowptr, cursor, partials, N, TOT);
  k_scatter<<<nbE, 256, 0, stream>>>(ei, cursor, col, E, N);
  int nbA = ((size_t)N * 64 + 255) / 256;
  k_agg1<<<nbA, 256, 0, stream>>>(rowptr, col, xv, embW, asv, adv, b1, buf1, N);
  k_mid<<<2048, 256, 0, stream>>>(buf1, W2, lng, lnb, as2w, ad2w, h2, as2, ad2, N);
  k_agg2<<<nbA, 256, 0, stream>>>(rowptr, col, h2, as2, ad2, b2, buf1, N);
  float* outh = (float*)d_out;
  k_final<<<2048, 256, 0, stream>>>(buf1, Wp, bp, outh, N);
  k_pool<<<NG, 64, 0, stream>>>(outh, bidx, outh + (size_t)N * CDIM, N);
}

// Round 2
// 846.273 us; speedup vs baseline: 1.6142x; 1.6142x over previous
//
#include <hip/hip_runtime.h>
#include <hip/hip_bf16.h>
#include <math.h>

#define H2C 128   // H*C
#define CDIM 64

typedef short s16x8 __attribute__((ext_vector_type(8)));
typedef float f32x4 __attribute__((ext_vector_type(4)));

static __device__ __forceinline__ float wred64(float x) {
#pragma unroll
  for (int off = 32; off; off >>= 1) x += __shfl_xor(x, off, 64);
  return x;
}
static __device__ __forceinline__ ushort f2bfu(float x) {
  __hip_bfloat16 b = __float2bfloat16(x);
  return *reinterpret_cast<ushort*>(&b);
}

// ---------------- layer-1 vocab tables: embW = emb @ W1, asv/adv per vocab ----
__global__ void k_embw(const float* __restrict__ emb, const float* __restrict__ W1,
                       const float* __restrict__ a_src, const float* __restrict__ a_dst,
                       float* __restrict__ embW, float* __restrict__ asv, float* __restrict__ adv)
{
  int v = blockIdx.x;
  int j = threadIdx.x;           // 0..127 (2 waves: wave0 = head0, wave1 = head1)
  const float* er = emb + v * CDIM;
  float acc = 0.f;
#pragma unroll
  for (int k = 0; k < CDIM; ++k) acc += er[k] * W1[k * H2C + j];
  embW[v * H2C + j] = acc;
  float ps = wred64(acc * a_src[j]);
  float pd = wred64(acc * a_dst[j]);
  if ((j & 63) == 0) {
    int h = j >> 6;
    asv[v * 2 + h] = ps;
    adv[v * 2 + h] = pd;
  }
}

// ---------------- W2 prep: w2bt[c][k] = bf16(W2[k][c]); wa = W2^T @ a ---------
__global__ void k_w2prep(const float* __restrict__ W2,
                         const float* __restrict__ as2w, const float* __restrict__ ad2w,
                         ushort* __restrict__ w2bt, float* __restrict__ was, float* __restrict__ wad)
{
  int k = blockIdx.x;       // 0..127
  int c = threadIdx.x;      // 0..127, wave h = c>>6
  float w = W2[k * H2C + c];
  w2bt[c * H2C + k] = f2bfu(w);
  int h = c >> 6;
  float s = wred64(w * as2w[c]);
  float d = wred64(w * ad2w[c]);
  if ((c & 63) == 0) { was[k * 2 + h] = s; wad[k * 2 + h] = d; }
}

// ---------------- CSR build --------------------------------------------------
__global__ void k_deg(const int* __restrict__ ei, int* __restrict__ deg, int E, int N)
{
  int e = blockIdx.x * blockDim.x + threadIdx.x;
  if (e >= E + N) return;
  int d = (e < E) ? ei[E + e] : (e - E);
  atomicAdd(&deg[d], 1);
}

__global__ void k_scan_a(const int* __restrict__ deg, int* __restrict__ rowptr,
                         int* __restrict__ partials, int n)
{
  __shared__ int sh[256];
  int t = threadIdx.x;
  int base = blockIdx.x * 1024 + t * 4;
  int v0 = 0, v1 = 0, v2 = 0, v3 = 0;
  if (base + 0 < n) v0 = deg[base + 0];
  if (base + 1 < n) v1 = deg[base + 1];
  if (base + 2 < n) v2 = deg[base + 2];
  if (base + 3 < n) v3 = deg[base + 3];
  int lsum = v0 + v1 + v2 + v3;
  sh[t] = lsum;
  __syncthreads();
  for (int offc = 1; offc < 256; offc <<= 1) {
    int x = (t >= offc) ? sh[t - offc] : 0;
    __syncthreads();
    sh[t] += x;
    __syncthreads();
  }
  int run = sh[t] - lsum;
  if (t == 255) partials[blockIdx.x] = sh[255];
  if (base + 0 < n) rowptr[base + 0] = run; run += v0;
  if (base + 1 < n) rowptr[base + 1] = run; run += v1;
  if (base + 2 < n) rowptr[base + 2] = run; run += v2;
  if (base + 3 < n) rowptr[base + 3] = run;
}

__global__ void k_scan_b(int* __restrict__ partials, int nb)
{
  __shared__ int sh[512];
  int t = threadIdx.x;
  int orig = (t < nb) ? partials[t] : 0;
  sh[t] = orig;
  __syncthreads();
  for (int offc = 1; offc < 512; offc <<= 1) {
    int x = (t >= offc) ? sh[t - offc] : 0;
    __syncthreads();
    sh[t] += x;
    __syncthreads();
  }
  if (t < nb) partials[t] = sh[t] - orig;   // exclusive block offsets
}

__global__ void k_scan_c(int* __restrict__ rowptr, int* __restrict__ cursor,
                         const int* __restrict__ partials, int n, int total)
{
  int i = blockIdx.x * blockDim.x + threadIdx.x;
  if (i == 0) rowptr[n] = total;
  if (i >= n) return;
  int r = rowptr[i] + partials[i >> 10];
  rowptr[i] = r;
  cursor[i] = r;
}

__global__ void k_scatter(const int* __restrict__ ei, int* __restrict__ cursor,
                          int* __restrict__ col, int E, int N)
{
  int e = blockIdx.x * blockDim.x + threadIdx.x;
  if (e >= E + N) return;
  int s, d;
  if (e < E) { s = ei[e]; d = ei[E + e]; } else { s = e - E; d = s; }
  int p = atomicAdd(&cursor[d], 1);
  col[p] = s;
}

// ------ GAT layer 1 + bias + LayerNorm + GELU + layer-2 alpha dots -----------
__global__ void k_agg1f(const int* __restrict__ rowptr, const int* __restrict__ col,
                        const int* __restrict__ xv, const float* __restrict__ embW,
                        const float* __restrict__ asv, const float* __restrict__ adv,
                        const float* __restrict__ b1,
                        const float* __restrict__ lng, const float* __restrict__ lnb,
                        const float* __restrict__ was, const float* __restrict__ wad,
                        ushort* __restrict__ g, float* __restrict__ as2,
                        float* __restrict__ ad2, int N)
{
  int wid = (blockIdx.x * blockDim.x + threadIdx.x) >> 6;
  if (wid >= N) return;
  int lane = threadIdx.x & 63;
  int start = rowptr[wid], end = rowptr[wid + 1];
  int vd = xv[wid];
  float ad0 = adv[vd * 2], ad1 = adv[vd * 2 + 1];
  float m0 = -INFINITY, m1 = -INFINITY, s0 = 0.f, s1 = 0.f, a0 = 0.f, a1 = 0.f;
  for (int p = start; p < end; ++p) {
    int s = col[p];
    int vs = xv[s];
    float e0 = asv[vs * 2]     + ad0; e0 = e0 >= 0.f ? e0 : 0.2f * e0;
    float e1 = asv[vs * 2 + 1] + ad1; e1 = e1 >= 0.f ? e1 : 0.2f * e1;
    float v0 = embW[vs * H2C + lane];
    float v1 = embW[vs * H2C + 64 + lane];
    float nm0 = fmaxf(m0, e0), nm1 = fmaxf(m1, e1);
    float sc0 = __expf(m0 - nm0), sc1 = __expf(m1 - nm1);
    float p0 = __expf(e0 - nm0),  p1 = __expf(e1 - nm1);
    s0 = s0 * sc0 + p0;           s1 = s1 * sc1 + p1;
    a0 = a0 * sc0 + p0 * v0;      a1 = a1 * sc1 + p1 * v1;
    m0 = nm0; m1 = nm1;
  }
  float x0 = a0 / (s0 + 1e-16f) + b1[lane];
  float x1 = a1 / (s1 + 1e-16f) + b1[64 + lane];
  // LayerNorm over the 128-vector held across the wave (2 elems/lane)
  float mean = wred64(x0 + x1) * (1.f / 128.f);
  float var  = wred64(x0 * x0 + x1 * x1) * (1.f / 128.f) - mean * mean;
  float rstd = rsqrtf(var + 1e-5f);
  float v0 = (x0 - mean) * rstd * lng[lane]      + lnb[lane];
  float v1 = (x1 - mean) * rstd * lng[64 + lane] + lnb[64 + lane];
  v0 = 0.5f * v0 * (1.f + erff(v0 * 0.70710678118654752f));
  v1 = 0.5f * v1 * (1.f + erff(v1 * 0.70710678118654752f));
  g[(size_t)wid * H2C + lane]      = f2bfu(v0);
  g[(size_t)wid * H2C + 64 + lane] = f2bfu(v1);
  // layer-2 alpha logits: h2 . a == g . (W2^T a)  (fp32 g, exact reassociation)
  float ps0 = wred64(v0 * was[lane * 2]     + v1 * was[(64 + lane) * 2]);
  float ps1 = wred64(v0 * was[lane * 2 + 1] + v1 * was[(64 + lane) * 2 + 1]);
  float pd0 = wred64(v0 * wad[lane * 2]     + v1 * wad[(64 + lane) * 2]);
  float pd1 = wred64(v0 * wad[lane * 2 + 1] + v1 * wad[(64 + lane) * 2 + 1]);
  if (lane == 0) {
    as2[wid * 2] = ps0; as2[wid * 2 + 1] = ps1;
    ad2[wid * 2] = pd0; ad2[wid * 2 + 1] = pd1;
  }
}

// ---------------- h2 = g @ W2 via bf16 MFMA ----------------------------------
// A (g) and B (W2^T) staged to LDS via global_load_lds (linear dest) with the
// source pre-swizzled by byte ^= (row&7)<<4; ds_read applies the same XOR.
__global__ void __launch_bounds__(256) k_gemm(const ushort* __restrict__ g,
                                              const ushort* __restrict__ w2bt,
                                              float* __restrict__ h2, int N)
{
  __shared__ ushort As[H2C * H2C];   // 32 KB: 128 rows x 128 bf16
  __shared__ ushort Bs[H2C * H2C];   // 32 KB: W2^T rows = output cols
  int tid = threadIdx.x, lane = tid & 63, wv = tid >> 6;
  size_t rbase = (size_t)blockIdx.x * 128;

#pragma unroll
  for (int it = 0; it < 8; ++it) {
    int cb = (it * 4 + wv) * 64;            // wave-uniform chunk base (16B chunks)
    int chunk = cb + lane;
    int row = chunk >> 4, kc = chunk & 15;
    int sc = (row << 4) | (kc ^ (row & 7)); // inverse-swizzled source chunk
    __builtin_amdgcn_global_load_lds(
        (const __attribute__((address_space(1))) void*)(g + rbase * H2C + (size_t)sc * 8),
        (__attribute__((address_space(3))) void*)(As + cb * 8), 16, 0, 0);
    __builtin_amdgcn_global_load_lds(
        (const __attribute__((address_space(1))) void*)(w2bt + (size_t)sc * 8),
        (__attribute__((address_space(3))) void*)(Bs + cb * 8), 16, 0, 0);
  }
  __syncthreads();

  f32x4 acc[2][8];
#pragma unroll
  for (int i = 0; i < 2; ++i)
#pragma unroll
    for (int j = 0; j < 8; ++j) acc[i][j] = (f32x4)0.f;

  int r15 = lane & 15, kg = lane >> 4;
#pragma unroll
  for (int ks = 0; ks < 4; ++ks) {
    int kc = ks * 4 + kg;
    s16x8 af[2], bfr[8];
#pragma unroll
    for (int mr = 0; mr < 2; ++mr) {
      int row = wv * 32 + mr * 16 + r15;
      af[mr] = *(const s16x8*)&As[row * H2C + (kc ^ (row & 7)) * 8];
    }
#pragma unroll
    for (int cf = 0; cf < 8; ++cf) {
      int row = cf * 16 + r15;
      bfr[cf] = *(const s16x8*)&Bs[row * H2C + (kc ^ (row & 7)) * 8];
    }
#pragma unroll
    for (int mr = 0; mr < 2; ++mr)
#pragma unroll
      for (int cf = 0; cf < 8; ++cf)
        acc[mr][cf] = __builtin_amdgcn_mfma_f32_16x16x32_bf16(af[mr], bfr[cf], acc[mr][cf], 0, 0, 0);
  }

#pragma unroll
  for (int mr = 0; mr < 2; ++mr) {
    int row0 = (int)rbase + wv * 32 + mr * 16 + kg * 4;
#pragma unroll
    for (int r = 0; r < 4; ++r) {
      int row = row0 + r;
      if (row < N) {
#pragma unroll
        for (int cf = 0; cf < 8; ++cf)
          h2[(size_t)row * H2C + cf * 16 + r15] = acc[mr][cf][r];
      }
    }
  }
}

// ---------------- GAT aggregation, layer 2 (per-node values) -----------------
__global__ void k_agg2(const int* __restrict__ rowptr, const int* __restrict__ col,
                       const float* __restrict__ h2,
                       const float* __restrict__ as2, const float* __restrict__ ad2,
                       const float* __restrict__ b2, float* __restrict__ out, int N)
{
  int wid = (blockIdx.x * blockDim.x + threadIdx.x) >> 6;
  if (wid >= N) return;
  int lane = threadIdx.x & 63;
  int start = rowptr[wid], end = rowptr[wid + 1];
  float ad0 = ad2[wid * 2], ad1 = ad2[wid * 2 + 1];
  float m0 = -INFINITY, m1 = -INFINITY, s0 = 0.f, s1 = 0.f, a0 = 0.f, a1 = 0.f;
  for (int p = start; p < end; ++p) {
    int s = col[p];
    float e0 = as2[s * 2]     + ad0; e0 = e0 >= 0.f ? e0 : 0.2f * e0;
    float e1 = as2[s * 2 + 1] + ad1; e1 = e1 >= 0.f ? e1 : 0.2f * e1;
    float v0 = h2[(size_t)s * H2C + lane];
    float v1 = h2[(size_t)s * H2C + 64 + lane];
    float nm0 = fmaxf(m0, e0), nm1 = fmaxf(m1, e1);
    float sc0 = __expf(m0 - nm0), sc1 = __expf(m1 - nm1);
    float p0 = __expf(e0 - nm0),  p1 = __expf(e1 - nm1);
    s0 = s0 * sc0 + p0;           s1 = s1 * sc1 + p1;
    a0 = a0 * sc0 + p0 * v0;      a1 = a1 * sc1 + p1 * v1;
    m0 = nm0; m1 = nm1;
  }
  out[(size_t)wid * H2C + lane]      = a0 / (s0 + 1e-16f) + b2[lane];
  out[(size_t)wid * H2C + 64 + lane] = a1 / (s1 + 1e-16f) + b2[64 + lane];
}

// ---------------- final projection @Wp + bp ----------------------------------
__global__ void __launch_bounds__(256)
k_final(const float* __restrict__ in, const float* __restrict__ Wp,
        const float* __restrict__ bp, float* __restrict__ outh, int N)
{
  __shared__ float wps[H2C * CDIM];
  for (int i = threadIdx.x; i < H2C * CDIM; i += 256) wps[i] = Wp[i];
  __syncthreads();
  int lane = threadIdx.x & 63;
  int w = threadIdx.x >> 6;
  int step = gridDim.x * 4;
  float bpc = bp[lane];
  for (int node = blockIdx.x * 4 + w; node < N; node += step) {
    float x0 = in[(size_t)node * H2C + lane];
    float x1 = in[(size_t)node * H2C + 64 + lane];
    float o = 0.f;
    for (int k = 0; k < 64; ++k) {
      float vk = __shfl(x0, k, 64);
      o += vk * wps[k * CDIM + lane];
    }
    for (int k = 0; k < 64; ++k) {
      float vk = __shfl(x1, k, 64);
      o += vk * wps[(64 + k) * CDIM + lane];
    }
    outh[(size_t)node * CDIM + lane] = o + bpc;
  }
}

// ---------------- graph mean pool (batch_idx is sorted) ----------------------
__global__ void k_pool(const float* __restrict__ h3, const int* __restrict__ bidx,
                       float* __restrict__ z, int N)
{
  int g = blockIdx.x;
  int lane = threadIdx.x;   // 64 threads
  int lo = 0, hi = N;
  while (lo < hi) { int mid = (lo + hi) >> 1; if (bidx[mid] < g) lo = mid + 1; else hi = mid; }
  int s0 = lo;
  hi = N;
  while (lo < hi) { int mid = (lo + hi) >> 1; if (bidx[mid] < g + 1) lo = mid + 1; else hi = mid; }
  int s1 = lo;
  float sum = 0.f;
  for (int i = s0; i < s1; ++i) sum += h3[(size_t)i * CDIM + lane];
  z[g * CDIM + lane] = sum / fmaxf((float)(s1 - s0), 1.f);
}

extern "C" void kernel_launch(void* const* d_in, const int* in_sizes, int n_in,
                              void* d_out, int out_size, void* d_ws, size_t ws_size,
                              hipStream_t stream)
{
  const int*   xv   = (const int*)d_in[0];
  const int*   ei   = (const int*)d_in[1];
  const int*   bidx = (const int*)d_in[2];
  const float* emb  = (const float*)d_in[3];
  const float* W1   = (const float*)d_in[4];
  const float* as1  = (const float*)d_in[5];
  const float* ad1  = (const float*)d_in[6];
  const float* b1   = (const float*)d_in[7];
  const float* lng  = (const float*)d_in[8];
  const float* lnb  = (const float*)d_in[9];
  const float* W2   = (const float*)d_in[10];
  const float* as2w = (const float*)d_in[11];
  const float* ad2w = (const float*)d_in[12];
  const float* b2   = (const float*)d_in[13];
  const float* Wp   = (const float*)d_in[14];
  const float* bp   = (const float*)d_in[15];

  const int N   = in_sizes[2];
  const int E   = in_sizes[1] / 2;
  const int V   = in_sizes[3] / CDIM;
  const int NG  = (out_size - N * CDIM) / CDIM;
  const int TOT = E + N;
  const int NB  = (N + 127) / 128;          // GEMM row tiles
  const int NPADROWS = NB * 128;            // g is readable up to here

  size_t off = 0;
  auto alloc = [&](size_t bytes) -> void* {
    void* p = (char*)d_ws + off;
    off += (bytes + 255) & ~(size_t)255;
    return p;
  };
  float* embW   = (float*)alloc((size_t)V * H2C * 4);
  float* asv    = (float*)alloc((size_t)V * 2 * 4);
  float* adv    = (float*)alloc((size_t)V * 2 * 4);
  ushort* w2bt  = (ushort*)alloc((size_t)H2C * H2C * 2);
  float* was    = (float*)alloc((size_t)H2C * 2 * 4);
  float* wad    = (float*)alloc((size_t)H2C * 2 * 4);
  // region shared by g (bf16, NPADROWS*128, ~25.6MB) and buf1 (fp32 N*128, 51.2MB):
  // g dead after k_gemm; buf1 first written by k_agg2 (after k_gemm). Sized for both.
  size_t rsz = (size_t)N * H2C * 4;
  if ((size_t)NPADROWS * H2C * 2 > rsz) rsz = (size_t)NPADROWS * H2C * 2;
  void*  region = alloc(rsz);
  ushort* g     = (ushort*)region;
  float*  buf1  = (float*)region;
  float* h2     = (float*)alloc((size_t)N * H2C * 4);
  float* as2    = (float*)alloc((size_t)N * 2 * 4);
  float* ad2    = (float*)alloc((size_t)N * 2 * 4);
  int*   deg    = (int*)alloc((size_t)N * 4);
  int*   rowptr = (int*)alloc(((size_t)N + 1) * 4);
  int*   cursor = (int*)alloc((size_t)N * 4);
  int*   col    = (int*)alloc((size_t)TOT * 4);
  int*   partials = (int*)alloc(512 * 4);
  (void)ws_size; (void)n_in;

  hipMemsetAsync(deg, 0, (size_t)N * 4, stream);
  k_embw<<<V, 128, 0, stream>>>(emb, W1, as1, ad1, embW, asv, adv);
  k_w2prep<<<H2C, H2C, 0, stream>>>(W2, as2w, ad2w, w2bt, was, wad);
  int nbE = (TOT + 255) / 256;
  k_deg<<<nbE, 256, 0, stream>>>(ei, deg, E, N);
  int nbS = (N + 1023) / 1024;
  k_scan_a<<<nbS, 256, 0, stream>>>(deg, rowptr, partials, N);
  k_scan_b<<<1, 512, 0, stream>>>(partials, nbS);
  k_scan_c<<<(N + 255) / 256, 256, 0, stream>>>(rowptr, cursor, partials, N, TOT);
  k_scatter<<<nbE, 256, 0, stream>>>(ei, cursor, col, E, N);
  int nbA = ((size_t)N * 64 + 255) / 256;
  k_agg1f<<<nbA, 256, 0, stream>>>(rowptr, col, xv, embW, asv, adv, b1,
                                   lng, lnb, was, wad, g, as2, ad2, N);
  k_gemm<<<NB, 256, 0, stream>>>(g, w2bt, h2, N);
  k_agg2<<<nbA, 256, 0, stream>>>(rowptr, col, h2, as2, ad2, b2, buf1, N);
  float* outh = (float*)d_out;
  k_final<<<2048, 256, 0, stream>>>(buf1, Wp, bp, outh, N);
  k_pool<<<NG, 64, 0, stream>>>(outh, bidx, outh + (size_t)N * CDIM, N);
}

// Round 3
// 695.877 us; speedup vs baseline: 1.9630x; 1.2161x over previous
//
#include <hip/hip_runtime.h>
#include <hip/hip_bf16.h>
#include <math.h>

#define H2C 128   // H*C
#define CDIM 64

typedef short s16x8 __attribute__((ext_vector_type(8)));
typedef float f32x4 __attribute__((ext_vector_type(4)));

static __device__ __forceinline__ float wred64(float x) {
#pragma unroll
  for (int off = 32; off; off >>= 1) x += __shfl_xor(x, off, 64);
  return x;
}
static __device__ __forceinline__ float wredmax64(float x) {
#pragma unroll
  for (int off = 32; off; off >>= 1) x = fmaxf(x, __shfl_xor(x, off, 64));
  return x;
}
static __device__ __forceinline__ ushort f2bfu(float x) {
  __hip_bfloat16 b = __float2bfloat16(x);
  return *reinterpret_cast<ushort*>(&b);
}
static __device__ __forceinline__ float bfu2f(ushort u) {
  unsigned int x = ((unsigned int)u) << 16;
  return __int_as_float((int)x);
}

// ---------------- layer-1 vocab tables: embW = emb @ W1, asv/adv per vocab ----
__global__ void k_embw(const float* __restrict__ emb, const float* __restrict__ W1,
                       const float* __restrict__ a_src, const float* __restrict__ a_dst,
                       float* __restrict__ embW, float* __restrict__ asv, float* __restrict__ adv)
{
  int v = blockIdx.x;
  int j = threadIdx.x;           // 0..127
  const float* er = emb + v * CDIM;
  float acc = 0.f;
#pragma unroll
  for (int k = 0; k < CDIM; ++k) acc += er[k] * W1[k * H2C + j];
  embW[v * H2C + j] = acc;
  float ps = wred64(acc * a_src[j]);
  float pd = wred64(acc * a_dst[j]);
  if ((j & 63) == 0) {
    int h = j >> 6;
    asv[v * 2 + h] = ps;
    adv[v * 2 + h] = pd;
  }
}

// ---------------- W2 prep: w2bt[c][k] = bf16(W2[k][c]); wa = W2^T @ a ---------
__global__ void k_w2prep(const float* __restrict__ W2,
                         const float* __restrict__ as2w, const float* __restrict__ ad2w,
                         ushort* __restrict__ w2bt, float* __restrict__ was, float* __restrict__ wad)
{
  int k = blockIdx.x;       // 0..127
  int c = threadIdx.x;      // 0..127
  float w = W2[k * H2C + c];
  w2bt[c * H2C + k] = f2bfu(w);
  int h = c >> 6;
  float s = wred64(w * as2w[c]);
  float d = wred64(w * ad2w[c]);
  if ((c & 63) == 0) { was[k * 2 + h] = s; wad[k * 2 + h] = d; }
}

// ---------------- Wp prep: wpbt[c][k] = bf16(Wp[k][c]) -----------------------
__global__ void k_wpprep(const float* __restrict__ Wp, ushort* __restrict__ wpbt)
{
  int k = blockIdx.x;       // 0..127
  int c = threadIdx.x;      // 0..63
  wpbt[c * H2C + k] = f2bfu(Wp[k * CDIM + c]);
}

// ---------------- CSR build --------------------------------------------------
__global__ void k_deg(const int* __restrict__ ei, int* __restrict__ deg, int E, int N)
{
  int e = blockIdx.x * blockDim.x + threadIdx.x;
  if (e >= E + N) return;
  int d = (e < E) ? ei[E + e] : (e - E);
  atomicAdd(&deg[d], 1);
}

__global__ void k_scan_a(const int* __restrict__ deg, int* __restrict__ rowptr,
                         int* __restrict__ partials, int n)
{
  __shared__ int sh[256];
  int t = threadIdx.x;
  int base = blockIdx.x * 1024 + t * 4;
  int v0 = 0, v1 = 0, v2 = 0, v3 = 0;
  if (base + 0 < n) v0 = deg[base + 0];
  if (base + 1 < n) v1 = deg[base + 1];
  if (base + 2 < n) v2 = deg[base + 2];
  if (base + 3 < n) v3 = deg[base + 3];
  int lsum = v0 + v1 + v2 + v3;
  sh[t] = lsum;
  __syncthreads();
  for (int offc = 1; offc < 256; offc <<= 1) {
    int x = (t >= offc) ? sh[t - offc] : 0;
    __syncthreads();
    sh[t] += x;
    __syncthreads();
  }
  int run = sh[t] - lsum;
  if (t == 255) partials[blockIdx.x] = sh[255];
  if (base + 0 < n) rowptr[base + 0] = run; run += v0;
  if (base + 1 < n) rowptr[base + 1] = run; run += v1;
  if (base + 2 < n) rowptr[base + 2] = run; run += v2;
  if (base + 3 < n) rowptr[base + 3] = run;
}

__global__ void k_scan_b(int* __restrict__ partials, int nb)
{
  __shared__ int sh[512];
  int t = threadIdx.x;
  int orig = (t < nb) ? partials[t] : 0;
  sh[t] = orig;
  __syncthreads();
  for (int offc = 1; offc < 512; offc <<= 1) {
    int x = (t >= offc) ? sh[t - offc] : 0;
    __syncthreads();
    sh[t] += x;
    __syncthreads();
  }
  if (t < nb) partials[t] = sh[t] - orig;   // exclusive block offsets
}

__global__ void k_scan_c(int* __restrict__ rowptr, int* __restrict__ cursor,
                         const int* __restrict__ partials, int n, int total)
{
  int i = blockIdx.x * blockDim.x + threadIdx.x;
  if (i == 0) rowptr[n] = total;
  if (i >= n) return;
  int r = rowptr[i] + partials[i >> 10];
  rowptr[i] = r;
  cursor[i] = r;
}

__global__ void k_scatter(const int* __restrict__ ei, const int* __restrict__ xv,
                          int* __restrict__ cursor, int* __restrict__ col,
                          ushort* __restrict__ colv, int E, int N)
{
  int e = blockIdx.x * blockDim.x + threadIdx.x;
  if (e >= E + N) return;
  int s, d;
  if (e < E) { s = ei[e]; d = ei[E + e]; } else { s = e - E; d = s; }
  int p = atomicAdd(&cursor[d], 1);
  col[p] = s;
  colv[p] = (ushort)xv[s];
}

// ---------------- per-node layer-1 logits ------------------------------------
__global__ void k_nodelog(const int* __restrict__ xv, const float2* __restrict__ asv,
                          const float2* __restrict__ adv,
                          float2* __restrict__ asn, float2* __restrict__ adn, int N)
{
  int i = blockIdx.x * blockDim.x + threadIdx.x;
  if (i >= N) return;
  int v = xv[i];
  asn[i] = asv[v];
  adn[i] = adv[v];
}

// ---------------- softmax pass: per-row max/sum, store exp(e-m) per edge -----
// wave per dst row, lanes parallel over edges
__global__ void k_alpha(const int* __restrict__ rowptr, const int* __restrict__ col,
                        const float2* __restrict__ asn, const float2* __restrict__ adn,
                        float2* __restrict__ alphaE, float2* __restrict__ rs, int N)
{
  int wid = (blockIdx.x * blockDim.x + threadIdx.x) >> 6;
  if (wid >= N) return;
  int lane = threadIdx.x & 63;
  int start = rowptr[wid], end = rowptr[wid + 1];
  float2 ad = adn[wid];
  float lm0 = -INFINITY, lm1 = -INFINITY;
  for (int p = start + lane; p < end; p += 64) {
    float2 a_ = asn[col[p]];
    float e0 = a_.x + ad.x; e0 = e0 >= 0.f ? e0 : 0.2f * e0;
    float e1 = a_.y + ad.y; e1 = e1 >= 0.f ? e1 : 0.2f * e1;
    lm0 = fmaxf(lm0, e0); lm1 = fmaxf(lm1, e1);
  }
  lm0 = wredmax64(lm0); lm1 = wredmax64(lm1);
  float s0 = 0.f, s1 = 0.f;
  for (int p = start + lane; p < end; p += 64) {
    float2 a_ = asn[col[p]];
    float e0 = a_.x + ad.x; e0 = e0 >= 0.f ? e0 : 0.2f * e0;
    float e1 = a_.y + ad.y; e1 = e1 >= 0.f ? e1 : 0.2f * e1;
    float ex0 = __expf(e0 - lm0), ex1 = __expf(e1 - lm1);
    s0 += ex0; s1 += ex1;
    alphaE[p] = make_float2(ex0, ex1);
  }
  s0 = wred64(s0); s1 = wred64(s1);
  if (lane == 0)
    rs[wid] = make_float2(1.f / (s0 + 1e-16f), 1.f / (s1 + 1e-16f));
}

// ------ layer-1 gather + bias + LayerNorm + GELU + layer-2 alpha dots --------
// lane holds channels c0=2*lane, c1=2*lane+1 (both in head lane>>5)
__global__ void k_gath1(const int* __restrict__ rowptr, const ushort* __restrict__ colv,
                        const float2* __restrict__ embW2,   // V x 64 float2
                        const float2* __restrict__ alphaE, const float2* __restrict__ rs,
                        const float* __restrict__ b1,
                        const float* __restrict__ lng, const float* __restrict__ lnb,
                        const float* __restrict__ was, const float* __restrict__ wad,
                        ushort2* __restrict__ g, float2* __restrict__ as2,
                        float2* __restrict__ ad2, int N)
{
  int wid = (blockIdx.x * blockDim.x + threadIdx.x) >> 6;
  if (wid >= N) return;
  int lane = threadIdx.x & 63;
  int start = rowptr[wid], end = rowptr[wid + 1];
  int head = lane >> 5;
  float acc0 = 0.f, acc1 = 0.f;
  for (int p = start; p < end; ++p) {
    int vs = colv[p];
    float2 ex = alphaE[p];
    float w = head ? ex.y : ex.x;
    float2 hv = embW2[vs * 64 + lane];
    acc0 += w * hv.x; acc1 += w * hv.y;
  }
  float2 r = rs[wid];
  float rr = head ? r.y : r.x;
  int c0 = lane * 2, c1 = c0 + 1;
  float x0 = acc0 * rr + b1[c0];
  float x1 = acc1 * rr + b1[c1];
  float mean = wred64(x0 + x1) * (1.f / 128.f);
  float var  = wred64(x0 * x0 + x1 * x1) * (1.f / 128.f) - mean * mean;
  float rstd = rsqrtf(var + 1e-5f);
  float v0 = (x0 - mean) * rstd * lng[c0] + lnb[c0];
  float v1 = (x1 - mean) * rstd * lng[c1] + lnb[c1];
  v0 = 0.5f * v0 * (1.f + erff(v0 * 0.70710678118654752f));
  v1 = 0.5f * v1 * (1.f + erff(v1 * 0.70710678118654752f));
  g[(size_t)wid * 64 + lane] = make_ushort2(f2bfu(v0), f2bfu(v1));
  // layer-2 alpha logits: h2 . a == g . (W2^T a)
  float ps0 = wred64(v0 * was[c0 * 2]     + v1 * was[c1 * 2]);
  float ps1 = wred64(v0 * was[c0 * 2 + 1] + v1 * was[c1 * 2 + 1]);
  float pd0 = wred64(v0 * wad[c0 * 2]     + v1 * wad[c1 * 2]);
  float pd1 = wred64(v0 * wad[c0 * 2 + 1] + v1 * wad[c1 * 2 + 1]);
  if (lane == 0) {
    as2[wid] = make_float2(ps0, ps1);
    ad2[wid] = make_float2(pd0, pd1);
  }
}

// ---------------- layer-2 gather + bias -> g2 (bf16) -------------------------
__global__ void k_gath2(const int* __restrict__ rowptr, const int* __restrict__ col,
                        const ushort2* __restrict__ h2b,
                        const float2* __restrict__ alphaE, const float2* __restrict__ rs,
                        const float* __restrict__ b2, ushort2* __restrict__ g2, int N)
{
  int wid = (blockIdx.x * blockDim.x + threadIdx.x) >> 6;
  if (wid >= N) return;
  int lane = threadIdx.x & 63;
  int start = rowptr[wid], end = rowptr[wid + 1];
  int head = lane >> 5;
  float acc0 = 0.f, acc1 = 0.f;
  for (int p = start; p < end; ++p) {
    int s = col[p];
    float2 ex = alphaE[p];
    float w = head ? ex.y : ex.x;
    ushort2 hv = h2b[(size_t)s * 64 + lane];
    acc0 += w * bfu2f(hv.x);
    acc1 += w * bfu2f(hv.y);
  }
  float2 r = rs[wid];
  float rr = head ? r.y : r.x;
  int c0 = lane * 2, c1 = c0 + 1;
  float o0 = acc0 * rr + b2[c0];
  float o1 = acc1 * rr + b2[c1];
  g2[(size_t)wid * 64 + lane] = make_ushort2(f2bfu(o0), f2bfu(o1));
}

// ---------------- h2b = bf16(g @ W2) via bf16 MFMA ---------------------------
__global__ void __launch_bounds__(256) k_gemm(const ushort* __restrict__ g,
                                              const ushort* __restrict__ w2bt,
                                              ushort* __restrict__ h2b, int N)
{
  __shared__ ushort As[H2C * H2C];
  __shared__ ushort Bs[H2C * H2C];
  int tid = threadIdx.x, lane = tid & 63, wv = tid >> 6;
  size_t rbase = (size_t)blockIdx.x * 128;

#pragma unroll
  for (int it = 0; it < 8; ++it) {
    int cb = (it * 4 + wv) * 64;
    int chunk = cb + lane;
    int row = chunk >> 4, kc = chunk & 15;
    int sc = (row << 4) | (kc ^ (row & 7));
    __builtin_amdgcn_global_load_lds(
        (const __attribute__((address_space(1))) void*)(g + rbase * H2C + (size_t)sc * 8),
        (__attribute__((address_space(3))) void*)(As + cb * 8), 16, 0, 0);
    __builtin_amdgcn_global_load_lds(
        (const __attribute__((address_space(1))) void*)(w2bt + (size_t)sc * 8),
        (__attribute__((address_space(3))) void*)(Bs + cb * 8), 16, 0, 0);
  }
  __syncthreads();

  f32x4 acc[2][8];
#pragma unroll
  for (int i = 0; i < 2; ++i)
#pragma unroll
    for (int j = 0; j < 8; ++j) acc[i][j] = (f32x4)0.f;

  int r15 = lane & 15, kg = lane >> 4;
#pragma unroll
  for (int ks = 0; ks < 4; ++ks) {
    int kc = ks * 4 + kg;
    s16x8 af[2], bfr[8];
#pragma unroll
    for (int mr = 0; mr < 2; ++mr) {
      int row = wv * 32 + mr * 16 + r15;
      af[mr] = *(const s16x8*)&As[row * H2C + (kc ^ (row & 7)) * 8];
    }
#pragma unroll
    for (int cf = 0; cf < 8; ++cf) {
      int row = cf * 16 + r15;
      bfr[cf] = *(const s16x8*)&Bs[row * H2C + (kc ^ (row & 7)) * 8];
    }
#pragma unroll
    for (int mr = 0; mr < 2; ++mr)
#pragma unroll
      for (int cf = 0; cf < 8; ++cf)
        acc[mr][cf] = __builtin_amdgcn_mfma_f32_16x16x32_bf16(af[mr], bfr[cf], acc[mr][cf], 0, 0, 0);
  }

#pragma unroll
  for (int mr = 0; mr < 2; ++mr) {
    int row0 = (int)rbase + wv * 32 + mr * 16 + kg * 4;
#pragma unroll
    for (int r = 0; r < 4; ++r) {
      int row = row0 + r;
      if (row < N) {
#pragma unroll
        for (int cf = 0; cf < 8; ++cf)
          h2b[(size_t)row * H2C + cf * 16 + r15] = f2bfu(acc[mr][cf][r]);
      }
    }
  }
}

// ---------------- h3 = g2 @ Wp + bp via bf16 MFMA (128 -> 64) ----------------
__global__ void __launch_bounds__(256) k_gemmP(const ushort* __restrict__ g2,
                                               const ushort* __restrict__ wpbt,
                                               const float* __restrict__ bp,
                                               float* __restrict__ h3, int N)
{
  __shared__ ushort As[H2C * H2C];     // 128 rows x 128 k
  __shared__ ushort Bs[CDIM * H2C];    // 64 cols x 128 k
  int tid = threadIdx.x, lane = tid & 63, wv = tid >> 6;
  size_t rbase = (size_t)blockIdx.x * 128;

#pragma unroll
  for (int it = 0; it < 8; ++it) {
    int cb = (it * 4 + wv) * 64;
    int chunk = cb + lane;
    int row = chunk >> 4, kc = chunk & 15;
    int sc = (row << 4) | (kc ^ (row & 7));
    __builtin_amdgcn_global_load_lds(
        (const __attribute__((address_space(1))) void*)(g2 + rbase * H2C + (size_t)sc * 8),
        (__attribute__((address_space(3))) void*)(As + cb * 8), 16, 0, 0);
  }
#pragma unroll
  for (int it = 0; it < 4; ++it) {
    int cb = (it * 4 + wv) * 64;
    int chunk = cb + lane;
    int row = chunk >> 4, kc = chunk & 15;
    int sc = (row << 4) | (kc ^ (row & 7));
    __builtin_amdgcn_global_load_lds(
        (const __attribute__((address_space(1))) void*)(wpbt + (size_t)sc * 8),
        (__attribute__((address_space(3))) void*)(Bs + cb * 8), 16, 0, 0);
  }
  __syncthreads();

  f32x4 acc[2][4];
#pragma unroll
  for (int i = 0; i < 2; ++i)
#pragma unroll
    for (int j = 0; j < 4; ++j) acc[i][j] = (f32x4)0.f;

  int r15 = lane & 15, kg = lane >> 4;
#pragma unroll
  for (int ks = 0; ks < 4; ++ks) {
    int kc = ks * 4 + kg;
    s16x8 af[2], bfr[4];
#pragma unroll
    for (int mr = 0; mr < 2; ++mr) {
      int row = wv * 32 + mr * 16 + r15;
      af[mr] = *(const s16x8*)&As[row * H2C + (kc ^ (row & 7)) * 8];
    }
#pragma unroll
    for (int cf = 0; cf < 4; ++cf) {
      int row = cf * 16 + r15;
      bfr[cf] = *(const s16x8*)&Bs[row * H2C + (kc ^ (row & 7)) * 8];
    }
#pragma unroll
    for (int mr = 0; mr < 2; ++mr)
#pragma unroll
      for (int cf = 0; cf < 4; ++cf)
        acc[mr][cf] = __builtin_amdgcn_mfma_f32_16x16x32_bf16(af[mr], bfr[cf], acc[mr][cf], 0, 0, 0);
  }

#pragma unroll
  for (int mr = 0; mr < 2; ++mr) {
    int row0 = (int)rbase + wv * 32 + mr * 16 + kg * 4;
#pragma unroll
    for (int r = 0; r < 4; ++r) {
      int row = row0 + r;
      if (row < N) {
#pragma unroll
        for (int cf = 0; cf < 4; ++cf)
          h3[(size_t)row * CDIM + cf * 16 + r15] = acc[mr][cf][r] + bp[cf * 16 + r15];
      }
    }
  }
}

// ---------------- graph mean pool (batch_idx is sorted) ----------------------
__global__ void k_pool(const float* __restrict__ h3, const int* __restrict__ bidx,
                       float* __restrict__ z, int N)
{
  int g = blockIdx.x;
  int lane = threadIdx.x;   // 64 threads
  int lo = 0, hi = N;
  while (lo < hi) { int mid = (lo + hi) >> 1; if (bidx[mid] < g) lo = mid + 1; else hi = mid; }
  int s0 = lo;
  hi = N;
  while (lo < hi) { int mid = (lo + hi) >> 1; if (bidx[mid] < g + 1) lo = mid + 1; else hi = mid; }
  int s1 = lo;
  float sum = 0.f;
  for (int i = s0; i < s1; ++i) sum += h3[(size_t)i * CDIM + lane];
  z[g * CDIM + lane] = sum / fmaxf((float)(s1 - s0), 1.f);
}

extern "C" void kernel_launch(void* const* d_in, const int* in_sizes, int n_in,
                              void* d_out, int out_size, void* d_ws, size_t ws_size,
                              hipStream_t stream)
{
  const int*   xv   = (const int*)d_in[0];
  const int*   ei   = (const int*)d_in[1];
  const int*   bidx = (const int*)d_in[2];
  const float* emb  = (const float*)d_in[3];
  const float* W1   = (const float*)d_in[4];
  const float* as1  = (const float*)d_in[5];
  const float* ad1  = (const float*)d_in[6];
  const float* b1   = (const float*)d_in[7];
  const float* lng  = (const float*)d_in[8];
  const float* lnb  = (const float*)d_in[9];
  const float* W2   = (const float*)d_in[10];
  const float* as2w = (const float*)d_in[11];
  const float* ad2w = (const float*)d_in[12];
  const float* b2   = (const float*)d_in[13];
  const float* Wp   = (const float*)d_in[14];
  const float* bp   = (const float*)d_in[15];

  const int N   = in_sizes[2];
  const int E   = in_sizes[1] / 2;
  const int V   = in_sizes[3] / CDIM;
  const int NG  = (out_size - N * CDIM) / CDIM;
  const int TOT = E + N;
  const int NB  = (N + 127) / 128;          // GEMM row tiles
  const size_t NPAD = (size_t)NB * 128;     // bf16 matrices readable up to here

  size_t off = 0;
  auto alloc = [&](size_t bytes) -> void* {
    void* p = (char*)d_ws + off;
    off += (bytes + 255) & ~(size_t)255;
    return p;
  };
  float*  embW   = (float*)alloc((size_t)V * H2C * 4);
  float*  asv    = (float*)alloc((size_t)V * 2 * 4);
  float*  adv    = (float*)alloc((size_t)V * 2 * 4);
  ushort* w2bt   = (ushort*)alloc((size_t)H2C * H2C * 2);
  ushort* wpbt   = (ushort*)alloc((size_t)CDIM * H2C * 2);
  float*  was    = (float*)alloc((size_t)H2C * 2 * 4);
  float*  wad    = (float*)alloc((size_t)H2C * 2 * 4);
  float2* asn    = (float2*)alloc((size_t)N * 8);
  float2* adn    = (float2*)alloc((size_t)N * 8);
  ushort* g      = (ushort*)alloc(NPAD * H2C * 2);
  ushort* h2b    = (ushort*)alloc((size_t)N * H2C * 2);
  ushort* g2     = (ushort*)alloc(NPAD * H2C * 2);
  float2* alphaE = (float2*)alloc((size_t)TOT * 8);
  float2* rs1    = (float2*)alloc((size_t)N * 8);
  float2* rs2    = (float2*)alloc((size_t)N * 8);
  float2* as2    = (float2*)alloc((size_t)N * 8);
  float2* ad2    = (float2*)alloc((size_t)N * 8);
  int*    deg    = (int*)alloc((size_t)N * 4);
  int*    rowptr = (int*)alloc(((size_t)N + 1) * 4);
  int*    cursor = (int*)alloc((size_t)N * 4);
  int*    col    = (int*)alloc((size_t)TOT * 4);
  ushort* colv   = (ushort*)alloc((size_t)TOT * 2);
  int*    partials = (int*)alloc(512 * 4);
  (void)ws_size; (void)n_in;

  hipMemsetAsync(deg, 0, (size_t)N * 4, stream);
  k_embw<<<V, 128, 0, stream>>>(emb, W1, as1, ad1, embW, asv, adv);
  k_w2prep<<<H2C, H2C, 0, stream>>>(W2, as2w, ad2w, w2bt, was, wad);
  k_wpprep<<<H2C, CDIM, 0, stream>>>(Wp, wpbt);
  int nbE = (TOT + 255) / 256;
  k_deg<<<nbE, 256, 0, stream>>>(ei, deg, E, N);
  int nbS = (N + 1023) / 1024;
  k_scan_a<<<nbS, 256, 0, stream>>>(deg, rowptr, partials, N);
  k_scan_b<<<1, 512, 0, stream>>>(partials, nbS);
  k_scan_c<<<(N + 255) / 256, 256, 0, stream>>>(rowptr, cursor, partials, N, TOT);
  k_scatter<<<nbE, 256, 0, stream>>>(ei, xv, cursor, col, colv, E, N);
  k_nodelog<<<(N + 255) / 256, 256, 0, stream>>>(xv, (const float2*)asv, (const float2*)adv,
                                                 asn, adn, N);
  int nbA = (int)(((size_t)N * 64 + 255) / 256);
  // layer 1
  k_alpha<<<nbA, 256, 0, stream>>>(rowptr, col, asn, adn, alphaE, rs1, N);
  k_gath1<<<nbA, 256, 0, stream>>>(rowptr, colv, (const float2*)embW, alphaE, rs1,
                                   b1, lng, lnb, was, wad, (ushort2*)g, as2, ad2, N);
  k_gemm<<<NB, 256, 0, stream>>>(g, w2bt, h2b, N);
  // layer 2
  k_alpha<<<nbA, 256, 0, stream>>>(rowptr, col, as2, ad2, alphaE, rs2, N);
  k_gath2<<<nbA, 256, 0, stream>>>(rowptr, col, (const ushort2*)h2b, alphaE, rs2,
                                   b2, (ushort2*)g2, N);
  float* outh = (float*)d_out;
  k_gemmP<<<NB, 256, 0, stream>>>(g2, wpbt, bp, outh, N);
  k_pool<<<NG, 64, 0, stream>>>(outh, bidx, outh + (size_t)N * CDIM, N);
}

// Round 4
// 531.616 us; speedup vs baseline: 2.5696x; 1.3090x over previous
//
#include <hip/hip_runtime.h>
#include <hip/hip_bf16.h>
#include <math.h>

#define H2C 128   // H*C
#define CDIM 64

typedef short s16x8 __attribute__((ext_vector_type(8)));
typedef unsigned short u16x8 __attribute__((ext_vector_type(8)));
typedef float f32x4 __attribute__((ext_vector_type(4)));

static __device__ __forceinline__ float wred64(float x) {
#pragma unroll
  for (int off = 32; off; off >>= 1) x += __shfl_xor(x, off, 64);
  return x;
}
static __device__ __forceinline__ float wredmax64(float x) {
#pragma unroll
  for (int off = 32; off; off >>= 1) x = fmaxf(x, __shfl_xor(x, off, 64));
  return x;
}
static __device__ __forceinline__ ushort f2bfu(float x) {
  __hip_bfloat16 b = __float2bfloat16(x);
  return *reinterpret_cast<ushort*>(&b);
}
static __device__ __forceinline__ float bfu2f(ushort u) {
  unsigned int x = ((unsigned int)u) << 16;
  return __int_as_float((int)x);
}

// ---------------- layer-1 vocab tables: embW(bf16) = emb @ W1, asv/adv -------
__global__ void k_embw(const float* __restrict__ emb, const float* __restrict__ W1,
                       const float* __restrict__ a_src, const float* __restrict__ a_dst,
                       ushort* __restrict__ embWb, float* __restrict__ asv, float* __restrict__ adv)
{
  int v = blockIdx.x;
  int j = threadIdx.x;           // 0..127
  const float* er = emb + v * CDIM;
  float acc = 0.f;
#pragma unroll
  for (int k = 0; k < CDIM; ++k) acc += er[k] * W1[k * H2C + j];
  embWb[v * H2C + j] = f2bfu(acc);
  float ps = wred64(acc * a_src[j]);
  float pd = wred64(acc * a_dst[j]);
  if ((j & 63) == 0) {
    int h = j >> 6;
    asv[v * 2 + h] = ps;
    adv[v * 2 + h] = pd;
  }
}

// ---------------- W2 prep: w2bt[c][k] = bf16(W2[k][c]); wa = W2^T @ a ---------
__global__ void k_w2prep(const float* __restrict__ W2,
                         const float* __restrict__ as2w, const float* __restrict__ ad2w,
                         ushort* __restrict__ w2bt, float* __restrict__ was, float* __restrict__ wad)
{
  int k = blockIdx.x;       // 0..127
  int c = threadIdx.x;      // 0..127
  float w = W2[k * H2C + c];
  w2bt[c * H2C + k] = f2bfu(w);
  int h = c >> 6;
  float s = wred64(w * as2w[c]);
  float d = wred64(w * ad2w[c]);
  if ((c & 63) == 0) { was[k * 2 + h] = s; wad[k * 2 + h] = d; }
}

// ---------------- Wp prep: wpbt[c][k] = bf16(Wp[k][c]) -----------------------
__global__ void k_wpprep(const float* __restrict__ Wp, ushort* __restrict__ wpbt)
{
  int k = blockIdx.x;       // 0..127
  int c = threadIdx.x;      // 0..63
  wpbt[c * H2C + k] = f2bfu(Wp[k * CDIM + c]);
}

// ---------------- CSR build --------------------------------------------------
__global__ void k_deg(const int* __restrict__ ei, int* __restrict__ deg, int E, int N)
{
  int e = blockIdx.x * blockDim.x + threadIdx.x;
  if (e >= E + N) return;
  int d = (e < E) ? ei[E + e] : (e - E);
  atomicAdd(&deg[d], 1);
}

__global__ void k_scan_a(const int* __restrict__ deg, int* __restrict__ rowptr,
                         int* __restrict__ partials, int n)
{
  __shared__ int sh[256];
  int t = threadIdx.x;
  int base = blockIdx.x * 1024 + t * 4;
  int v0 = 0, v1 = 0, v2 = 0, v3 = 0;
  if (base + 0 < n) v0 = deg[base + 0];
  if (base + 1 < n) v1 = deg[base + 1];
  if (base + 2 < n) v2 = deg[base + 2];
  if (base + 3 < n) v3 = deg[base + 3];
  int lsum = v0 + v1 + v2 + v3;
  sh[t] = lsum;
  __syncthreads();
  for (int offc = 1; offc < 256; offc <<= 1) {
    int x = (t >= offc) ? sh[t - offc] : 0;
    __syncthreads();
    sh[t] += x;
    __syncthreads();
  }
  int run = sh[t] - lsum;
  if (t == 255) partials[blockIdx.x] = sh[255];
  if (base + 0 < n) rowptr[base + 0] = run; run += v0;
  if (base + 1 < n) rowptr[base + 1] = run; run += v1;
  if (base + 2 < n) rowptr[base + 2] = run; run += v2;
  if (base + 3 < n) rowptr[base + 3] = run;
}

__global__ void k_scan_b(int* __restrict__ partials, int nb)
{
  __shared__ int sh[512];
  int t = threadIdx.x;
  int orig = (t < nb) ? partials[t] : 0;
  sh[t] = orig;
  __syncthreads();
  for (int offc = 1; offc < 512; offc <<= 1) {
    int x = (t >= offc) ? sh[t - offc] : 0;
    __syncthreads();
    sh[t] += x;
    __syncthreads();
  }
  if (t < nb) partials[t] = sh[t] - orig;   // exclusive block offsets
}

__global__ void k_scan_c(int* __restrict__ rowptr, int* __restrict__ cursor,
                         const int* __restrict__ partials, int n, int total)
{
  int i = blockIdx.x * blockDim.x + threadIdx.x;
  if (i == 0) rowptr[n] = total;
  if (i >= n) return;
  int r = rowptr[i] + partials[i >> 10];
  rowptr[i] = r;
  cursor[i] = r;
}

__global__ void k_scatter(const int* __restrict__ ei, const int* __restrict__ xv,
                          int* __restrict__ cursor, int* __restrict__ col,
                          ushort* __restrict__ colv, int E, int N)
{
  int e = blockIdx.x * blockDim.x + threadIdx.x;
  if (e >= E + N) return;
  int s, d;
  if (e < E) { s = ei[e]; d = ei[E + e]; } else { s = e - E; d = s; }
  int p = atomicAdd(&cursor[d], 1);
  col[p] = s;
  colv[p] = (ushort)xv[s];
}

// ===== fused layer-1: softmax + gather + bias + LN + GELU + layer-2 dots =====
// wave per row (grid-stride). Pass A/B: lanes parallel over edges (max, sum).
// Pass C: 16-lane groups, 4 edges in flight; lane holds 8 channels (16B loads).
__global__ void __launch_bounds__(256)
k_gath1(const int* __restrict__ rowptr, const ushort* __restrict__ colv,
        const int* __restrict__ xv,
        const float2* __restrict__ asv, const float2* __restrict__ adv,
        const ushort* __restrict__ embWb,
        const float* __restrict__ b1, const float* __restrict__ lng,
        const float* __restrict__ lnb,
        const float* __restrict__ was, const float* __restrict__ wad,
        ushort* __restrict__ g, float2* __restrict__ as2,
        float2* __restrict__ ad2, int N)
{
  int lane = threadIdx.x & 63;
  int wv = (blockIdx.x * blockDim.x + threadIdx.x) >> 6;
  int nw = (gridDim.x * blockDim.x) >> 6;
  int grp = lane >> 4, l16 = lane & 15;
  int headL = l16 >> 3;               // channels cb..cb+7 all in this head
  int cb = l16 * 8;
  float b1c[8], lngc[8], lnbc[8], was0[8], was1[8], wad0[8], wad1[8];
#pragma unroll
  for (int j = 0; j < 8; ++j) {
    b1c[j] = b1[cb + j]; lngc[j] = lng[cb + j]; lnbc[j] = lnb[cb + j];
    was0[j] = was[(cb + j) * 2]; was1[j] = was[(cb + j) * 2 + 1];
    wad0[j] = wad[(cb + j) * 2]; wad1[j] = wad[(cb + j) * 2 + 1];
  }
  for (int wid = wv; wid < N; wid += nw) {
    int start = rowptr[wid], end = rowptr[wid + 1];
    float2 ad = adv[xv[wid]];
    float m0 = -INFINITY, m1 = -INFINITY;
    for (int p = start + lane; p < end; p += 64) {
      float2 a_ = asv[colv[p]];
      float e0 = a_.x + ad.x; e0 = e0 >= 0.f ? e0 : 0.2f * e0;
      float e1 = a_.y + ad.y; e1 = e1 >= 0.f ? e1 : 0.2f * e1;
      m0 = fmaxf(m0, e0); m1 = fmaxf(m1, e1);
    }
    m0 = wredmax64(m0); m1 = wredmax64(m1);
    float s0 = 0.f, s1 = 0.f;
    for (int p = start + lane; p < end; p += 64) {
      float2 a_ = asv[colv[p]];
      float e0 = a_.x + ad.x; e0 = e0 >= 0.f ? e0 : 0.2f * e0;
      float e1 = a_.y + ad.y; e1 = e1 >= 0.f ? e1 : 0.2f * e1;
      s0 += __expf(e0 - m0); s1 += __expf(e1 - m1);
    }
    s0 = wred64(s0); s1 = wred64(s1);
    float mh  = headL ? m1 : m0;
    float adh = headL ? ad.y : ad.x;
    float rr  = headL ? 1.f / (s1 + 1e-16f) : 1.f / (s0 + 1e-16f);
    float acc[8] = {0.f, 0.f, 0.f, 0.f, 0.f, 0.f, 0.f, 0.f};
    for (int p = start + grp; p < end; p += 4) {
      int idx = colv[p];
      float2 a_ = asv[idx];
      float e = (headL ? a_.y : a_.x) + adh; e = e >= 0.f ? e : 0.2f * e;
      float ex = __expf(e - mh);
      u16x8 v = *(const u16x8*)&embWb[(size_t)idx * H2C + cb];
#pragma unroll
      for (int j = 0; j < 8; ++j) acc[j] += ex * bfu2f(v[j]);
    }
#pragma unroll
    for (int j = 0; j < 8; ++j) {
      acc[j] += __shfl_xor(acc[j], 16, 64);
      acc[j] += __shfl_xor(acc[j], 32, 64);
    }
    float x[8], sum = 0.f, ssq = 0.f;
#pragma unroll
    for (int j = 0; j < 8; ++j) {
      x[j] = acc[j] * rr + b1c[j];
      sum += x[j]; ssq += x[j] * x[j];
    }
    float mean = wred64(sum) * (1.f / 512.f);          // 4x group redundancy
    float var  = wred64(ssq) * (1.f / 512.f) - mean * mean;
    float rstd = rsqrtf(var + 1e-5f);
    float ps0 = 0.f, ps1 = 0.f, pd0 = 0.f, pd1 = 0.f;
    u16x8 gv;
#pragma unroll
    for (int j = 0; j < 8; ++j) {
      float t = (x[j] - mean) * rstd * lngc[j] + lnbc[j];
      t = 0.5f * t * (1.f + erff(t * 0.70710678118654752f));
      gv[j] = f2bfu(t);
      ps0 += t * was0[j]; ps1 += t * was1[j];
      pd0 += t * wad0[j]; pd1 += t * wad1[j];
    }
    if (lane < 16) *(u16x8*)&g[(size_t)wid * H2C + cb] = gv;
    ps0 = wred64(ps0) * 0.25f; ps1 = wred64(ps1) * 0.25f;
    pd0 = wred64(pd0) * 0.25f; pd1 = wred64(pd1) * 0.25f;
    if (lane == 0) {
      as2[wid] = make_float2(ps0, ps1);
      ad2[wid] = make_float2(pd0, pd1);
    }
  }
}

// ===== fused layer-2: softmax + gather + bias -> g2 (bf16) ====================
__global__ void __launch_bounds__(256)
k_gath2(const int* __restrict__ rowptr, const int* __restrict__ col,
        const float2* __restrict__ as2, const float2* __restrict__ ad2,
        const ushort* __restrict__ h2b, const float* __restrict__ b2,
        ushort* __restrict__ g2, int N)
{
  int lane = threadIdx.x & 63;
  int wv = (blockIdx.x * blockDim.x + threadIdx.x) >> 6;
  int nw = (gridDim.x * blockDim.x) >> 6;
  int grp = lane >> 4, l16 = lane & 15;
  int headL = l16 >> 3;
  int cb = l16 * 8;
  float b2c[8];
#pragma unroll
  for (int j = 0; j < 8; ++j) b2c[j] = b2[cb + j];
  for (int wid = wv; wid < N; wid += nw) {
    int start = rowptr[wid], end = rowptr[wid + 1];
    float2 ad = ad2[wid];
    float m0 = -INFINITY, m1 = -INFINITY;
    for (int p = start + lane; p < end; p += 64) {
      float2 a_ = as2[col[p]];
      float e0 = a_.x + ad.x; e0 = e0 >= 0.f ? e0 : 0.2f * e0;
      float e1 = a_.y + ad.y; e1 = e1 >= 0.f ? e1 : 0.2f * e1;
      m0 = fmaxf(m0, e0); m1 = fmaxf(m1, e1);
    }
    m0 = wredmax64(m0); m1 = wredmax64(m1);
    float s0 = 0.f, s1 = 0.f;
    for (int p = start + lane; p < end; p += 64) {
      float2 a_ = as2[col[p]];
      float e0 = a_.x + ad.x; e0 = e0 >= 0.f ? e0 : 0.2f * e0;
      float e1 = a_.y + ad.y; e1 = e1 >= 0.f ? e1 : 0.2f * e1;
      s0 += __expf(e0 - m0); s1 += __expf(e1 - m1);
    }
    s0 = wred64(s0); s1 = wred64(s1);
    float mh  = headL ? m1 : m0;
    float adh = headL ? ad.y : ad.x;
    float rr  = headL ? 1.f / (s1 + 1e-16f) : 1.f / (s0 + 1e-16f);
    float acc[8] = {0.f, 0.f, 0.f, 0.f, 0.f, 0.f, 0.f, 0.f};
    for (int p = start + grp; p < end; p += 4) {
      int idx = col[p];
      float2 a_ = as2[idx];
      float e = (headL ? a_.y : a_.x) + adh; e = e >= 0.f ? e : 0.2f * e;
      float ex = __expf(e - mh);
      u16x8 v = *(const u16x8*)&h2b[(size_t)idx * H2C + cb];
#pragma unroll
      for (int j = 0; j < 8; ++j) acc[j] += ex * bfu2f(v[j]);
    }
#pragma unroll
    for (int j = 0; j < 8; ++j) {
      acc[j] += __shfl_xor(acc[j], 16, 64);
      acc[j] += __shfl_xor(acc[j], 32, 64);
    }
    u16x8 gv;
#pragma unroll
    for (int j = 0; j < 8; ++j) gv[j] = f2bfu(acc[j] * rr + b2c[j]);
    if (lane < 16) *(u16x8*)&g2[(size_t)wid * H2C + cb] = gv;
  }
}

// ---------------- h2b = bf16(g @ W2) via bf16 MFMA ---------------------------
__global__ void __launch_bounds__(256) k_gemm(const ushort* __restrict__ g,
                                              const ushort* __restrict__ w2bt,
                                              ushort* __restrict__ h2b, int N)
{
  __shared__ ushort As[H2C * H2C];
  __shared__ ushort Bs[H2C * H2C];
  int tid = threadIdx.x, lane = tid & 63, wv = tid >> 6;
  size_t rbase = (size_t)blockIdx.x * 128;

#pragma unroll
  for (int it = 0; it < 8; ++it) {
    int cb = (it * 4 + wv) * 64;
    int chunk = cb + lane;
    int row = chunk >> 4, kc = chunk & 15;
    int sc = (row << 4) | (kc ^ (row & 7));
    __builtin_amdgcn_global_load_lds(
        (const __attribute__((address_space(1))) void*)(g + rbase * H2C + (size_t)sc * 8),
        (__attribute__((address_space(3))) void*)(As + cb * 8), 16, 0, 0);
    __builtin_amdgcn_global_load_lds(
        (const __attribute__((address_space(1))) void*)(w2bt + (size_t)sc * 8),
        (__attribute__((address_space(3))) void*)(Bs + cb * 8), 16, 0, 0);
  }
  __syncthreads();

  f32x4 acc[2][8];
#pragma unroll
  for (int i = 0; i < 2; ++i)
#pragma unroll
    for (int j = 0; j < 8; ++j) acc[i][j] = (f32x4)0.f;

  int r15 = lane & 15, kg = lane >> 4;
#pragma unroll
  for (int ks = 0; ks < 4; ++ks) {
    int kc = ks * 4 + kg;
    s16x8 af[2], bfr[8];
#pragma unroll
    for (int mr = 0; mr < 2; ++mr) {
      int row = wv * 32 + mr * 16 + r15;
      af[mr] = *(const s16x8*)&As[row * H2C + (kc ^ (row & 7)) * 8];
    }
#pragma unroll
    for (int cf = 0; cf < 8; ++cf) {
      int row = cf * 16 + r15;
      bfr[cf] = *(const s16x8*)&Bs[row * H2C + (kc ^ (row & 7)) * 8];
    }
#pragma unroll
    for (int mr = 0; mr < 2; ++mr)
#pragma unroll
      for (int cf = 0; cf < 8; ++cf)
        acc[mr][cf] = __builtin_amdgcn_mfma_f32_16x16x32_bf16(af[mr], bfr[cf], acc[mr][cf], 0, 0, 0);
  }

#pragma unroll
  for (int mr = 0; mr < 2; ++mr) {
    int row0 = (int)rbase + wv * 32 + mr * 16 + kg * 4;
#pragma unroll
    for (int r = 0; r < 4; ++r) {
      int row = row0 + r;
      if (row < N) {
#pragma unroll
        for (int cf = 0; cf < 8; ++cf)
          h2b[(size_t)row * H2C + cf * 16 + r15] = f2bfu(acc[mr][cf][r]);
      }
    }
  }
}

// ---------------- h3 = g2 @ Wp + bp via bf16 MFMA (128 -> 64) ----------------
__global__ void __launch_bounds__(256) k_gemmP(const ushort* __restrict__ g2,
                                               const ushort* __restrict__ wpbt,
                                               const float* __restrict__ bp,
                                               float* __restrict__ h3, int N)
{
  __shared__ ushort As[H2C * H2C];
  __shared__ ushort Bs[CDIM * H2C];
  int tid = threadIdx.x, lane = tid & 63, wv = tid >> 6;
  size_t rbase = (size_t)blockIdx.x * 128;

#pragma unroll
  for (int it = 0; it < 8; ++it) {
    int cb = (it * 4 + wv) * 64;
    int chunk = cb + lane;
    int row = chunk >> 4, kc = chunk & 15;
    int sc = (row << 4) | (kc ^ (row & 7));
    __builtin_amdgcn_global_load_lds(
        (const __attribute__((address_space(1))) void*)(g2 + rbase * H2C + (size_t)sc * 8),
        (__attribute__((address_space(3))) void*)(As + cb * 8), 16, 0, 0);
  }
#pragma unroll
  for (int it = 0; it < 4; ++it) {
    int cb = (it * 4 + wv) * 64;
    int chunk = cb + lane;
    int row = chunk >> 4, kc = chunk & 15;
    int sc = (row << 4) | (kc ^ (row & 7));
    __builtin_amdgcn_global_load_lds(
        (const __attribute__((address_space(1))) void*)(wpbt + (size_t)sc * 8),
        (__attribute__((address_space(3))) void*)(Bs + cb * 8), 16, 0, 0);
  }
  __syncthreads();

  f32x4 acc[2][4];
#pragma unroll
  for (int i = 0; i < 2; ++i)
#pragma unroll
    for (int j = 0; j < 4; ++j) acc[i][j] = (f32x4)0.f;

  int r15 = lane & 15, kg = lane >> 4;
#pragma unroll
  for (int ks = 0; ks < 4; ++ks) {
    int kc = ks * 4 + kg;
    s16x8 af[2], bfr[4];
#pragma unroll
    for (int mr = 0; mr < 2; ++mr) {
      int row = wv * 32 + mr * 16 + r15;
      af[mr] = *(const s16x8*)&As[row * H2C + (kc ^ (row & 7)) * 8];
    }
#pragma unroll
    for (int cf = 0; cf < 4; ++cf) {
      int row = cf * 16 + r15;
      bfr[cf] = *(const s16x8*)&Bs[row * H2C + (kc ^ (row & 7)) * 8];
    }
#pragma unroll
    for (int mr = 0; mr < 2; ++mr)
#pragma unroll
      for (int cf = 0; cf < 4; ++cf)
        acc[mr][cf] = __builtin_amdgcn_mfma_f32_16x16x32_bf16(af[mr], bfr[cf], acc[mr][cf], 0, 0, 0);
  }

#pragma unroll
  for (int mr = 0; mr < 2; ++mr) {
    int row0 = (int)rbase + wv * 32 + mr * 16 + kg * 4;
#pragma unroll
    for (int r = 0; r < 4; ++r) {
      int row = row0 + r;
      if (row < N) {
#pragma unroll
        for (int cf = 0; cf < 4; ++cf)
          h3[(size_t)row * CDIM + cf * 16 + r15] = acc[mr][cf][r] + bp[cf * 16 + r15];
      }
    }
  }
}

// ---------------- graph mean pool (batch_idx is sorted) ----------------------
__global__ void k_pool(const float* __restrict__ h3, const int* __restrict__ bidx,
                       float* __restrict__ z, int N)
{
  int g = blockIdx.x;
  int lane = threadIdx.x;   // 64 threads
  int lo = 0, hi = N;
  while (lo < hi) { int mid = (lo + hi) >> 1; if (bidx[mid] < g) lo = mid + 1; else hi = mid; }
  int s0 = lo;
  hi = N;
  while (lo < hi) { int mid = (lo + hi) >> 1; if (bidx[mid] < g + 1) lo = mid + 1; else hi = mid; }
  int s1 = lo;
  float sum = 0.f;
  for (int i = s0; i < s1; ++i) sum += h3[(size_t)i * CDIM + lane];
  z[g * CDIM + lane] = sum / fmaxf((float)(s1 - s0), 1.f);
}

extern "C" void kernel_launch(void* const* d_in, const int* in_sizes, int n_in,
                              void* d_out, int out_size, void* d_ws, size_t ws_size,
                              hipStream_t stream)
{
  const int*   xv   = (const int*)d_in[0];
  const int*   ei   = (const int*)d_in[1];
  const int*   bidx = (const int*)d_in[2];
  const float* emb  = (const float*)d_in[3];
  const float* W1   = (const float*)d_in[4];
  const float* as1  = (const float*)d_in[5];
  const float* ad1  = (const float*)d_in[6];
  const float* b1   = (const float*)d_in[7];
  const float* lng  = (const float*)d_in[8];
  const float* lnb  = (const float*)d_in[9];
  const float* W2   = (const float*)d_in[10];
  const float* as2w = (const float*)d_in[11];
  const float* ad2w = (const float*)d_in[12];
  const float* b2   = (const float*)d_in[13];
  const float* Wp   = (const float*)d_in[14];
  const float* bp   = (const float*)d_in[15];

  const int N   = in_sizes[2];
  const int E   = in_sizes[1] / 2;
  const int V   = in_sizes[3] / CDIM;
  const int NG  = (out_size - N * CDIM) / CDIM;
  const int TOT = E + N;
  const int NB  = (N + 127) / 128;          // GEMM row tiles
  const size_t NPAD = (size_t)NB * 128;     // bf16 matrices readable up to here

  size_t off = 0;
  auto alloc = [&](size_t bytes) -> void* {
    void* p = (char*)d_ws + off;
    off += (bytes + 255) & ~(size_t)255;
    return p;
  };
  ushort* embWb  = (ushort*)alloc((size_t)V * H2C * 2);
  float*  asv    = (float*)alloc((size_t)V * 2 * 4);
  float*  adv    = (float*)alloc((size_t)V * 2 * 4);
  ushort* w2bt   = (ushort*)alloc((size_t)H2C * H2C * 2);
  ushort* wpbt   = (ushort*)alloc((size_t)CDIM * H2C * 2);
  float*  was    = (float*)alloc((size_t)H2C * 2 * 4);
  float*  wad    = (float*)alloc((size_t)H2C * 2 * 4);
  ushort* g      = (ushort*)alloc(NPAD * H2C * 2);
  ushort* h2b    = (ushort*)alloc((size_t)N * H2C * 2);
  ushort* g2     = (ushort*)alloc(NPAD * H2C * 2);
  float2* as2    = (float2*)alloc((size_t)N * 8);
  float2* ad2    = (float2*)alloc((size_t)N * 8);
  int*    deg    = (int*)alloc((size_t)N * 4);
  int*    rowptr = (int*)alloc(((size_t)N + 1) * 4);
  int*    cursor = (int*)alloc((size_t)N * 4);
  int*    col    = (int*)alloc((size_t)TOT * 4);
  ushort* colv   = (ushort*)alloc((size_t)TOT * 2);
  int*    partials = (int*)alloc(512 * 4);
  (void)ws_size; (void)n_in;

  hipMemsetAsync(deg, 0, (size_t)N * 4, stream);
  k_embw<<<V, 128, 0, stream>>>(emb, W1, as1, ad1, embWb, asv, adv);
  k_w2prep<<<H2C, H2C, 0, stream>>>(W2, as2w, ad2w, w2bt, was, wad);
  k_wpprep<<<H2C, CDIM, 0, stream>>>(Wp, wpbt);
  int nbE = (TOT + 255) / 256;
  k_deg<<<nbE, 256, 0, stream>>>(ei, deg, E, N);
  int nbS = (N + 1023) / 1024;
  k_scan_a<<<nbS, 256, 0, stream>>>(deg, rowptr, partials, N);
  k_scan_b<<<1, 512, 0, stream>>>(partials, nbS);
  k_scan_c<<<(N + 255) / 256, 256, 0, stream>>>(rowptr, cursor, partials, N, TOT);
  k_scatter<<<nbE, 256, 0, stream>>>(ei, xv, cursor, col, colv, E, N);
  // layer 1 (fused softmax+gather+LN+GELU+dots)
  k_gath1<<<2048, 256, 0, stream>>>(rowptr, colv, xv, (const float2*)asv,
                                    (const float2*)adv, embWb, b1, lng, lnb,
                                    was, wad, g, as2, ad2, N);
  k_gemm<<<NB, 256, 0, stream>>>(g, w2bt, h2b, N);
  // layer 2 (fused softmax+gather+bias)
  k_gath2<<<2048, 256, 0, stream>>>(rowptr, col, as2, ad2, h2b, b2, g2, N);
  float* outh = (float*)d_out;
  k_gemmP<<<NB, 256, 0, stream>>>(g2, wpbt, bp, outh, N);
  k_pool<<<NG, 64, 0, stream>>>(outh, bidx, outh + (size_t)N * CDIM, N);
}

// Round 5
// 423.315 us; speedup vs baseline: 3.2269x; 1.2558x over previous
//
#include <hip/hip_runtime.h>
#include <hip/hip_bf16.h>
#include <math.h>

#define H2C 128   // H*C
#define CDIM 64

typedef short s16x8 __attribute__((ext_vector_type(8)));
typedef unsigned short u16x8 __attribute__((ext_vector_type(8)));
typedef float f32x4 __attribute__((ext_vector_type(4)));

static __device__ __forceinline__ float wred64(float x) {
#pragma unroll
  for (int off = 32; off; off >>= 1) x += __shfl_xor(x, off, 64);
  return x;
}
static __device__ __forceinline__ ushort f2bfu(float x) {
  __hip_bfloat16 b = __float2bfloat16(x);
  return *reinterpret_cast<ushort*>(&b);
}
static __device__ __forceinline__ float bfu2f(ushort u) {
  unsigned int x = ((unsigned int)u) << 16;
  return __int_as_float((int)x);
}

// ---------------- layer-1 vocab tables: embW(bf16) = emb @ W1, asv/adv -------
__global__ void k_embw(const float* __restrict__ emb, const float* __restrict__ W1,
                       const float* __restrict__ a_src, const float* __restrict__ a_dst,
                       ushort* __restrict__ embWb, float* __restrict__ asv, float* __restrict__ adv)
{
  int v = blockIdx.x;
  int j = threadIdx.x;           // 0..127
  const float* er = emb + v * CDIM;
  float acc = 0.f;
#pragma unroll
  for (int k = 0; k < CDIM; ++k) acc += er[k] * W1[k * H2C + j];
  embWb[v * H2C + j] = f2bfu(acc);
  float ps = wred64(acc * a_src[j]);
  float pd = wred64(acc * a_dst[j]);
  if ((j & 63) == 0) {
    int h = j >> 6;
    asv[v * 2 + h] = ps;
    adv[v * 2 + h] = pd;
  }
}

// ---------------- W2 prep: w2bt[c][k] = bf16(W2[k][c]); wa = W2^T @ a ---------
__global__ void k_w2prep(const float* __restrict__ W2,
                         const float* __restrict__ as2w, const float* __restrict__ ad2w,
                         ushort* __restrict__ w2bt, float* __restrict__ was, float* __restrict__ wad)
{
  int k = blockIdx.x;       // 0..127
  int c = threadIdx.x;      // 0..127
  float w = W2[k * H2C + c];
  w2bt[c * H2C + k] = f2bfu(w);
  int h = c >> 6;
  float s = wred64(w * as2w[c]);
  float d = wred64(w * ad2w[c]);
  if ((c & 63) == 0) { was[k * 2 + h] = s; wad[k * 2 + h] = d; }
}

// ---------------- Wp prep: wpbt[c][k] = bf16(Wp[k][c]) -----------------------
__global__ void k_wpprep(const float* __restrict__ Wp, ushort* __restrict__ wpbt)
{
  int k = blockIdx.x;       // 0..127
  int c = threadIdx.x;      // 0..63
  wpbt[c * H2C + k] = f2bfu(Wp[k * CDIM + c]);
}

// ---------------- CSR build --------------------------------------------------
__global__ void k_deg(const int* __restrict__ ei, int* __restrict__ deg, int E, int N)
{
  int e = blockIdx.x * blockDim.x + threadIdx.x;
  if (e >= E + N) return;
  int d = (e < E) ? ei[E + e] : (e - E);
  atomicAdd(&deg[d], 1);
}

__global__ void k_scan_a(const int* __restrict__ deg, int* __restrict__ rowptr,
                         int* __restrict__ partials, int n)
{
  __shared__ int sh[256];
  int t = threadIdx.x;
  int base = blockIdx.x * 1024 + t * 4;
  int v0 = 0, v1 = 0, v2 = 0, v3 = 0;
  if (base + 0 < n) v0 = deg[base + 0];
  if (base + 1 < n) v1 = deg[base + 1];
  if (base + 2 < n) v2 = deg[base + 2];
  if (base + 3 < n) v3 = deg[base + 3];
  int lsum = v0 + v1 + v2 + v3;
  sh[t] = lsum;
  __syncthreads();
  for (int offc = 1; offc < 256; offc <<= 1) {
    int x = (t >= offc) ? sh[t - offc] : 0;
    __syncthreads();
    sh[t] += x;
    __syncthreads();
  }
  int run = sh[t] - lsum;
  if (t == 255) partials[blockIdx.x] = sh[255];
  if (base + 0 < n) rowptr[base + 0] = run; run += v0;
  if (base + 1 < n) rowptr[base + 1] = run; run += v1;
  if (base + 2 < n) rowptr[base + 2] = run; run += v2;
  if (base + 3 < n) rowptr[base + 3] = run;
}

__global__ void k_scan_b(int* __restrict__ partials, int nb)
{
  __shared__ int sh[512];
  int t = threadIdx.x;
  int orig = (t < nb) ? partials[t] : 0;
  sh[t] = orig;
  __syncthreads();
  for (int offc = 1; offc < 512; offc <<= 1) {
    int x = (t >= offc) ? sh[t - offc] : 0;
    __syncthreads();
    sh[t] += x;
    __syncthreads();
  }
  if (t < nb) partials[t] = sh[t] - orig;   // exclusive block offsets
}

__global__ void k_scan_c(int* __restrict__ rowptr, int* __restrict__ cursor,
                         const int* __restrict__ partials, int n, int total)
{
  int i = blockIdx.x * blockDim.x + threadIdx.x;
  if (i == 0) rowptr[n] = total;
  if (i >= n) return;
  int r = rowptr[i] + partials[i >> 10];
  rowptr[i] = r;
  cursor[i] = r;
}

__global__ void k_scatter(const int* __restrict__ ei, const int* __restrict__ xv,
                          int* __restrict__ cursor, int* __restrict__ col,
                          ushort* __restrict__ colv, int E, int N)
{
  int e = blockIdx.x * blockDim.x + threadIdx.x;
  if (e >= E + N) return;
  int s, d;
  if (e < E) { s = ei[e]; d = ei[E + e]; } else { s = e - E; d = s; }
  int p = atomicAdd(&cursor[d], 1);
  col[p] = s;
  colv[p] = (ushort)xv[s];
}

// ===== fused layer-1: single-pass softmax-gather + bias + LN + GELU + dots ===
// wave per row (grid-stride); 16-lane groups each own one edge (4 in flight);
// lane holds 8 channels (16B loads). No max subtraction (logits bounded).
__global__ void __launch_bounds__(256)
k_gath1(const int* __restrict__ rowptr, const ushort* __restrict__ colv,
        const int* __restrict__ xv,
        const float2* __restrict__ asv, const float2* __restrict__ adv,
        const ushort* __restrict__ embWb,
        const float* __restrict__ b1, const float* __restrict__ lng,
        const float* __restrict__ lnb,
        const float* __restrict__ was, const float* __restrict__ wad,
        ushort* __restrict__ g, float2* __restrict__ as2,
        float2* __restrict__ ad2, int N)
{
  int lane = threadIdx.x & 63;
  int wv = (blockIdx.x * blockDim.x + threadIdx.x) >> 6;
  int nw = (gridDim.x * blockDim.x) >> 6;
  int grp = lane >> 4, l16 = lane & 15;
  int headL = l16 >> 3;               // channels cb..cb+7 all in this head
  int cb = l16 * 8;
  float b1c[8], lngc[8], lnbc[8], was0[8], was1[8], wad0[8], wad1[8];
#pragma unroll
  for (int j = 0; j < 8; ++j) {
    b1c[j] = b1[cb + j]; lngc[j] = lng[cb + j]; lnbc[j] = lnb[cb + j];
    was0[j] = was[(cb + j) * 2]; was1[j] = was[(cb + j) * 2 + 1];
    wad0[j] = wad[(cb + j) * 2]; wad1[j] = wad[(cb + j) * 2 + 1];
  }
  for (int wid = wv; wid < N; wid += nw) {
    int start = rowptr[wid], end = rowptr[wid + 1];
    float2 ad = adv[xv[wid]];
    float adh = headL ? ad.y : ad.x;
    float acc[8] = {0.f, 0.f, 0.f, 0.f, 0.f, 0.f, 0.f, 0.f};
    float s = 0.f;
    for (int p = start + grp; p < end; p += 4) {
      int idx = colv[p];
      float2 a_ = asv[idx];
      float e = (headL ? a_.y : a_.x) + adh; e = e >= 0.f ? e : 0.2f * e;
      float ex = __expf(e);
      s += ex;
      u16x8 v = *(const u16x8*)&embWb[(size_t)idx * H2C + cb];
#pragma unroll
      for (int j = 0; j < 8; ++j) acc[j] += ex * bfu2f(v[j]);
    }
#pragma unroll
    for (int j = 0; j < 8; ++j) {
      acc[j] += __shfl_xor(acc[j], 16, 64);
      acc[j] += __shfl_xor(acc[j], 32, 64);
    }
    s += __shfl_xor(s, 16, 64);
    s += __shfl_xor(s, 32, 64);
    float rr = 1.f / (s + 1e-16f);
    float x[8], sum = 0.f, ssq = 0.f;
#pragma unroll
    for (int j = 0; j < 8; ++j) {
      x[j] = acc[j] * rr + b1c[j];
      sum += x[j]; ssq += x[j] * x[j];
    }
    float mean = wred64(sum) * (1.f / 512.f);          // 4x group redundancy
    float var  = wred64(ssq) * (1.f / 512.f) - mean * mean;
    float rstd = rsqrtf(var + 1e-5f);
    float ps0 = 0.f, ps1 = 0.f, pd0 = 0.f, pd1 = 0.f;
    u16x8 gv;
#pragma unroll
    for (int j = 0; j < 8; ++j) {
      float t = (x[j] - mean) * rstd * lngc[j] + lnbc[j];
      t = 0.5f * t * (1.f + erff(t * 0.70710678118654752f));
      gv[j] = f2bfu(t);
      ps0 += t * was0[j]; ps1 += t * was1[j];
      pd0 += t * wad0[j]; pd1 += t * wad1[j];
    }
    if (lane < 16) *(u16x8*)&g[(size_t)wid * H2C + cb] = gv;
    ps0 = wred64(ps0) * 0.25f; ps1 = wred64(ps1) * 0.25f;
    pd0 = wred64(pd0) * 0.25f; pd1 = wred64(pd1) * 0.25f;
    if (lane == 0) {
      as2[wid] = make_float2(ps0, ps1);
      ad2[wid] = make_float2(pd0, pd1);
    }
  }
}

// ===== fused layer-2: single-pass softmax-gather + bias -> g2 (bf16) =========
__global__ void __launch_bounds__(256)
k_gath2(const int* __restrict__ rowptr, const int* __restrict__ col,
        const float2* __restrict__ as2, const float2* __restrict__ ad2,
        const ushort* __restrict__ h2b, const float* __restrict__ b2,
        ushort* __restrict__ g2, int N)
{
  int lane = threadIdx.x & 63;
  int wv = (blockIdx.x * blockDim.x + threadIdx.x) >> 6;
  int nw = (gridDim.x * blockDim.x) >> 6;
  int grp = lane >> 4, l16 = lane & 15;
  int headL = l16 >> 3;
  int cb = l16 * 8;
  float b2c[8];
#pragma unroll
  for (int j = 0; j < 8; ++j) b2c[j] = b2[cb + j];
  for (int wid = wv; wid < N; wid += nw) {
    int start = rowptr[wid], end = rowptr[wid + 1];
    float2 ad = ad2[wid];
    float adh = headL ? ad.y : ad.x;
    float acc[8] = {0.f, 0.f, 0.f, 0.f, 0.f, 0.f, 0.f, 0.f};
    float s = 0.f;
    for (int p = start + grp; p < end; p += 4) {
      int idx = col[p];
      float2 a_ = as2[idx];
      float e = (headL ? a_.y : a_.x) + adh; e = e >= 0.f ? e : 0.2f * e;
      float ex = __expf(e);
      s += ex;
      u16x8 v = *(const u16x8*)&h2b[(size_t)idx * H2C + cb];
#pragma unroll
      for (int j = 0; j < 8; ++j) acc[j] += ex * bfu2f(v[j]);
    }
#pragma unroll
    for (int j = 0; j < 8; ++j) {
      acc[j] += __shfl_xor(acc[j], 16, 64);
      acc[j] += __shfl_xor(acc[j], 32, 64);
    }
    s += __shfl_xor(s, 16, 64);
    s += __shfl_xor(s, 32, 64);
    float rr = 1.f / (s + 1e-16f);
    u16x8 gv;
#pragma unroll
    for (int j = 0; j < 8; ++j) gv[j] = f2bfu(acc[j] * rr + b2c[j]);
    if (lane < 16) *(u16x8*)&g2[(size_t)wid * H2C + cb] = gv;
  }
}

// ---------------- h2b = bf16(g @ W2) via bf16 MFMA ---------------------------
__global__ void __launch_bounds__(256) k_gemm(const ushort* __restrict__ g,
                                              const ushort* __restrict__ w2bt,
                                              ushort* __restrict__ h2b, int N)
{
  __shared__ ushort As[H2C * H2C];
  __shared__ ushort Bs[H2C * H2C];
  int tid = threadIdx.x, lane = tid & 63, wv = tid >> 6;
  size_t rbase = (size_t)blockIdx.x * 128;

#pragma unroll
  for (int it = 0; it < 8; ++it) {
    int cb = (it * 4 + wv) * 64;
    int chunk = cb + lane;
    int row = chunk >> 4, kc = chunk & 15;
    int sc = (row << 4) | (kc ^ (row & 7));
    __builtin_amdgcn_global_load_lds(
        (const __attribute__((address_space(1))) void*)(g + rbase * H2C + (size_t)sc * 8),
        (__attribute__((address_space(3))) void*)(As + cb * 8), 16, 0, 0);
    __builtin_amdgcn_global_load_lds(
        (const __attribute__((address_space(1))) void*)(w2bt + (size_t)sc * 8),
        (__attribute__((address_space(3))) void*)(Bs + cb * 8), 16, 0, 0);
  }
  __syncthreads();

  f32x4 acc[2][8];
#pragma unroll
  for (int i = 0; i < 2; ++i)
#pragma unroll
    for (int j = 0; j < 8; ++j) acc[i][j] = (f32x4)0.f;

  int r15 = lane & 15, kg = lane >> 4;
#pragma unroll
  for (int ks = 0; ks < 4; ++ks) {
    int kc = ks * 4 + kg;
    s16x8 af[2], bfr[8];
#pragma unroll
    for (int mr = 0; mr < 2; ++mr) {
      int row = wv * 32 + mr * 16 + r15;
      af[mr] = *(const s16x8*)&As[row * H2C + (kc ^ (row & 7)) * 8];
    }
#pragma unroll
    for (int cf = 0; cf < 8; ++cf) {
      int row = cf * 16 + r15;
      bfr[cf] = *(const s16x8*)&Bs[row * H2C + (kc ^ (row & 7)) * 8];
    }
#pragma unroll
    for (int mr = 0; mr < 2; ++mr)
#pragma unroll
      for (int cf = 0; cf < 8; ++cf)
        acc[mr][cf] = __builtin_amdgcn_mfma_f32_16x16x32_bf16(af[mr], bfr[cf], acc[mr][cf], 0, 0, 0);
  }

#pragma unroll
  for (int mr = 0; mr < 2; ++mr) {
    int row0 = (int)rbase + wv * 32 + mr * 16 + kg * 4;
#pragma unroll
    for (int r = 0; r < 4; ++r) {
      int row = row0 + r;
      if (row < N) {
#pragma unroll
        for (int cf = 0; cf < 8; ++cf)
          h2b[(size_t)row * H2C + cf * 16 + r15] = f2bfu(acc[mr][cf][r]);
      }
    }
  }
}

// ---------------- h3 = g2 @ Wp + bp via bf16 MFMA (128 -> 64) ----------------
__global__ void __launch_bounds__(256) k_gemmP(const ushort* __restrict__ g2,
                                               const ushort* __restrict__ wpbt,
                                               const float* __restrict__ bp,
                                               float* __restrict__ h3, int N)
{
  __shared__ ushort As[H2C * H2C];
  __shared__ ushort Bs[CDIM * H2C];
  int tid = threadIdx.x, lane = tid & 63, wv = tid >> 6;
  size_t rbase = (size_t)blockIdx.x * 128;

#pragma unroll
  for (int it = 0; it < 8; ++it) {
    int cb = (it * 4 + wv) * 64;
    int chunk = cb + lane;
    int row = chunk >> 4, kc = chunk & 15;
    int sc = (row << 4) | (kc ^ (row & 7));
    __builtin_amdgcn_global_load_lds(
        (const __attribute__((address_space(1))) void*)(g2 + rbase * H2C + (size_t)sc * 8),
        (__attribute__((address_space(3))) void*)(As + cb * 8), 16, 0, 0);
  }
#pragma unroll
  for (int it = 0; it < 4; ++it) {
    int cb = (it * 4 + wv) * 64;
    int chunk = cb + lane;
    int row = chunk >> 4, kc = chunk & 15;
    int sc = (row << 4) | (kc ^ (row & 7));
    __builtin_amdgcn_global_load_lds(
        (const __attribute__((address_space(1))) void*)(wpbt + (size_t)sc * 8),
        (__attribute__((address_space(3))) void*)(Bs + cb * 8), 16, 0, 0);
  }
  __syncthreads();

  f32x4 acc[2][4];
#pragma unroll
  for (int i = 0; i < 2; ++i)
#pragma unroll
    for (int j = 0; j < 4; ++j) acc[i][j] = (f32x4)0.f;

  int r15 = lane & 15, kg = lane >> 4;
#pragma unroll
  for (int ks = 0; ks < 4; ++ks) {
    int kc = ks * 4 + kg;
    s16x8 af[2], bfr[4];
#pragma unroll
    for (int mr = 0; mr < 2; ++mr) {
      int row = wv * 32 + mr * 16 + r15;
      af[mr] = *(const s16x8*)&As[row * H2C + (kc ^ (row & 7)) * 8];
    }
#pragma unroll
    for (int cf = 0; cf < 4; ++cf) {
      int row = cf * 16 + r15;
      bfr[cf] = *(const s16x8*)&Bs[row * H2C + (kc ^ (row & 7)) * 8];
    }
#pragma unroll
    for (int mr = 0; mr < 2; ++mr)
#pragma unroll
      for (int cf = 0; cf < 4; ++cf)
        acc[mr][cf] = __builtin_amdgcn_mfma_f32_16x16x32_bf16(af[mr], bfr[cf], acc[mr][cf], 0, 0, 0);
  }

#pragma unroll
  for (int mr = 0; mr < 2; ++mr) {
    int row0 = (int)rbase + wv * 32 + mr * 16 + kg * 4;
#pragma unroll
    for (int r = 0; r < 4; ++r) {
      int row = row0 + r;
      if (row < N) {
#pragma unroll
        for (int cf = 0; cf < 4; ++cf)
          h3[(size_t)row * CDIM + cf * 16 + r15] = acc[mr][cf][r] + bp[cf * 16 + r15];
      }
    }
  }
}

// ---------------- graph mean pool (batch_idx is sorted), 4 waves/graph -------
__global__ void __launch_bounds__(256)
k_pool(const float* __restrict__ h3, const int* __restrict__ bidx,
       float* __restrict__ z, int N)
{
  __shared__ float sh[4][64];
  int g = blockIdx.x;
  int lane = threadIdx.x & 63;
  int w = threadIdx.x >> 6;
  int lo = 0, hi = N;
  while (lo < hi) { int mid = (lo + hi) >> 1; if (bidx[mid] < g) lo = mid + 1; else hi = mid; }
  int s0 = lo;
  hi = N;
  while (lo < hi) { int mid = (lo + hi) >> 1; if (bidx[mid] < g + 1) lo = mid + 1; else hi = mid; }
  int s1 = lo;
  float sum = 0.f;
  for (int i = s0 + w; i < s1; i += 4) sum += h3[(size_t)i * CDIM + lane];
  sh[w][lane] = sum;
  __syncthreads();
  if (w == 0) {
    sum = sh[0][lane] + sh[1][lane] + sh[2][lane] + sh[3][lane];
    z[g * CDIM + lane] = sum / fmaxf((float)(s1 - s0), 1.f);
  }
}

extern "C" void kernel_launch(void* const* d_in, const int* in_sizes, int n_in,
                              void* d_out, int out_size, void* d_ws, size_t ws_size,
                              hipStream_t stream)
{
  const int*   xv   = (const int*)d_in[0];
  const int*   ei   = (const int*)d_in[1];
  const int*   bidx = (const int*)d_in[2];
  const float* emb  = (const float*)d_in[3];
  const float* W1   = (const float*)d_in[4];
  const float* as1  = (const float*)d_in[5];
  const float* ad1  = (const float*)d_in[6];
  const float* b1   = (const float*)d_in[7];
  const float* lng  = (const float*)d_in[8];
  const float* lnb  = (const float*)d_in[9];
  const float* W2   = (const float*)d_in[10];
  const float* as2w = (const float*)d_in[11];
  const float* ad2w = (const float*)d_in[12];
  const float* b2   = (const float*)d_in[13];
  const float* Wp   = (const float*)d_in[14];
  const float* bp   = (const float*)d_in[15];

  const int N   = in_sizes[2];
  const int E   = in_sizes[1] / 2;
  const int V   = in_sizes[3] / CDIM;
  const int NG  = (out_size - N * CDIM) / CDIM;
  const int TOT = E + N;
  const int NB  = (N + 127) / 128;          // GEMM row tiles
  const size_t NPAD = (size_t)NB * 128;     // bf16 matrices readable up to here

  size_t off = 0;
  auto alloc = [&](size_t bytes) -> void* {
    void* p = (char*)d_ws + off;
    off += (bytes + 255) & ~(size_t)255;
    return p;
  };
  ushort* embWb  = (ushort*)alloc((size_t)V * H2C * 2);
  float*  asv    = (float*)alloc((size_t)V * 2 * 4);
  float*  adv    = (float*)alloc((size_t)V * 2 * 4);
  ushort* w2bt   = (ushort*)alloc((size_t)H2C * H2C * 2);
  ushort* wpbt   = (ushort*)alloc((size_t)CDIM * H2C * 2);
  float*  was    = (float*)alloc((size_t)H2C * 2 * 4);
  float*  wad    = (float*)alloc((size_t)H2C * 2 * 4);
  ushort* g      = (ushort*)alloc(NPAD * H2C * 2);
  ushort* h2b    = (ushort*)alloc((size_t)N * H2C * 2);
  ushort* g2     = (ushort*)alloc(NPAD * H2C * 2);
  float2* as2    = (float2*)alloc((size_t)N * 8);
  float2* ad2    = (float2*)alloc((size_t)N * 8);
  int*    deg    = (int*)alloc((size_t)N * 4);
  int*    rowptr = (int*)alloc(((size_t)N + 1) * 4);
  int*    cursor = (int*)alloc((size_t)N * 4);
  int*    col    = (int*)alloc((size_t)TOT * 4);
  ushort* colv   = (ushort*)alloc((size_t)TOT * 2);
  int*    partials = (int*)alloc(512 * 4);
  (void)ws_size; (void)n_in;

  hipMemsetAsync(deg, 0, (size_t)N * 4, stream);
  k_embw<<<V, 128, 0, stream>>>(emb, W1, as1, ad1, embWb, asv, adv);
  k_w2prep<<<H2C, H2C, 0, stream>>>(W2, as2w, ad2w, w2bt, was, wad);
  k_wpprep<<<H2C, CDIM, 0, stream>>>(Wp, wpbt);
  int nbE = (TOT + 255) / 256;
  k_deg<<<nbE, 256, 0, stream>>>(ei, deg, E, N);
  int nbS = (N + 1023) / 1024;
  k_scan_a<<<nbS, 256, 0, stream>>>(deg, rowptr, partials, N);
  k_scan_b<<<1, 512, 0, stream>>>(partials, nbS);
  k_scan_c<<<(N + 255) / 256, 256, 0, stream>>>(rowptr, cursor, partials, N, TOT);
  k_scatter<<<nbE, 256, 0, stream>>>(ei, xv, cursor, col, colv, E, N);
  // layer 1 (single-pass softmax-gather + LN + GELU + dots)
  k_gath1<<<2048, 256, 0, stream>>>(rowptr, colv, xv, (const float2*)asv,
                                    (const float2*)adv, embWb, b1, lng, lnb,
                                    was, wad, g, as2, ad2, N);
  k_gemm<<<NB, 256, 0, stream>>>(g, w2bt, h2b, N);
  // layer 2 (single-pass softmax-gather + bias)
  k_gath2<<<2048, 256, 0, stream>>>(rowptr, col, as2, ad2, h2b, b2, g2, N);
  float* outh = (float*)d_out;
  k_gemmP<<<NB, 256, 0, stream>>>(g2, wpbt, bp, outh, N);
  k_pool<<<NG, 256, 0, stream>>>(outh, bidx, outh + (size_t)N * CDIM, N);
}

// Round 6
// 371.238 us; speedup vs baseline: 3.6796x; 1.1403x over previous
//
#include <hip/hip_runtime.h>
#include <hip/hip_bf16.h>
#include <math.h>

#define H2C 128   // H*C
#define CDIM 64

typedef short s16x8 __attribute__((ext_vector_type(8)));
typedef unsigned short u16x8 __attribute__((ext_vector_type(8)));
typedef float f32x4 __attribute__((ext_vector_type(4)));

static __device__ __forceinline__ float wred64(float x) {
#pragma unroll
  for (int off = 32; off; off >>= 1) x += __shfl_xor(x, off, 64);
  return x;
}
static __device__ __forceinline__ ushort f2bfu(float x) {
  __hip_bfloat16 b = __float2bfloat16(x);
  return *reinterpret_cast<ushort*>(&b);
}
static __device__ __forceinline__ float bfu2f(ushort u) {
  unsigned int x = ((unsigned int)u) << 16;
  return __int_as_float((int)x);
}
// Abramowitz-Stegun 7.1.26, |err| <= 1.5e-7
static __device__ __forceinline__ float erf_fast(float x) {
  float ax = fabsf(x);
  float t = __fdividef(1.f, 1.f + 0.3275911f * ax);
  float y = t * (0.254829592f + t * (-0.284496736f +
            t * (1.421413741f + t * (-1.453152027f + t * 1.061405429f))));
  float e = 1.f - y * __expf(-ax * ax);
  return copysignf(e, x);
}

// ---------------- layer-1 vocab tables: embW(bf16) = emb @ W1, asv/adv -------
__global__ void k_embw(const float* __restrict__ emb, const float* __restrict__ W1,
                       const float* __restrict__ a_src, const float* __restrict__ a_dst,
                       ushort* __restrict__ embWb, float* __restrict__ asv, float* __restrict__ adv)
{
  int v = blockIdx.x;
  int j = threadIdx.x;           // 0..127
  const float* er = emb + v * CDIM;
  float acc = 0.f;
#pragma unroll
  for (int k = 0; k < CDIM; ++k) acc += er[k] * W1[k * H2C + j];
  embWb[v * H2C + j] = f2bfu(acc);
  float ps = wred64(acc * a_src[j]);
  float pd = wred64(acc * a_dst[j]);
  if ((j & 63) == 0) {
    int h = j >> 6;
    asv[v * 2 + h] = ps;
    adv[v * 2 + h] = pd;
  }
}

// ---------------- W2 prep: w2bt[c][k] = bf16(W2[k][c]); wa = W2^T @ a ---------
__global__ void k_w2prep(const float* __restrict__ W2,
                         const float* __restrict__ as2w, const float* __restrict__ ad2w,
                         ushort* __restrict__ w2bt, float* __restrict__ was, float* __restrict__ wad)
{
  int k = blockIdx.x;       // 0..127
  int c = threadIdx.x;      // 0..127
  float w = W2[k * H2C + c];
  w2bt[c * H2C + k] = f2bfu(w);
  int h = c >> 6;
  float s = wred64(w * as2w[c]);
  float d = wred64(w * ad2w[c]);
  if ((c & 63) == 0) { was[k * 2 + h] = s; wad[k * 2 + h] = d; }
}

// ---------------- Wp prep: wpbt[c][k] = bf16(Wp[k][c]) -----------------------
__global__ void k_wpprep(const float* __restrict__ Wp, ushort* __restrict__ wpbt)
{
  int k = blockIdx.x;       // 0..127
  int c = threadIdx.x;      // 0..63
  wpbt[c * H2C + k] = f2bfu(Wp[k * CDIM + c]);
}

// ---------------- CSR build --------------------------------------------------
__global__ void k_deg(const int* __restrict__ ei, int* __restrict__ deg, int E, int N)
{
  int e = blockIdx.x * blockDim.x + threadIdx.x;
  if (e >= E + N) return;
  int d = (e < E) ? ei[E + e] : (e - E);
  atomicAdd(&deg[d], 1);
}

__global__ void k_scan_a(const int* __restrict__ deg, int* __restrict__ rowptr,
                         int* __restrict__ partials, int n)
{
  __shared__ int sh[256];
  int t = threadIdx.x;
  int base = blockIdx.x * 1024 + t * 4;
  int v0 = 0, v1 = 0, v2 = 0, v3 = 0;
  if (base + 0 < n) v0 = deg[base + 0];
  if (base + 1 < n) v1 = deg[base + 1];
  if (base + 2 < n) v2 = deg[base + 2];
  if (base + 3 < n) v3 = deg[base + 3];
  int lsum = v0 + v1 + v2 + v3;
  sh[t] = lsum;
  __syncthreads();
  for (int offc = 1; offc < 256; offc <<= 1) {
    int x = (t >= offc) ? sh[t - offc] : 0;
    __syncthreads();
    sh[t] += x;
    __syncthreads();
  }
  int run = sh[t] - lsum;
  if (t == 255) partials[blockIdx.x] = sh[255];
  if (base + 0 < n) rowptr[base + 0] = run; run += v0;
  if (base + 1 < n) rowptr[base + 1] = run; run += v1;
  if (base + 2 < n) rowptr[base + 2] = run; run += v2;
  if (base + 3 < n) rowptr[base + 3] = run;
}

__global__ void k_scan_b(int* __restrict__ partials, int nb)
{
  __shared__ int sh[512];
  int t = threadIdx.x;
  int orig = (t < nb) ? partials[t] : 0;
  sh[t] = orig;
  __syncthreads();
  for (int offc = 1; offc < 512; offc <<= 1) {
    int x = (t >= offc) ? sh[t - offc] : 0;
    __syncthreads();
    sh[t] += x;
    __syncthreads();
  }
  if (t < nb) partials[t] = sh[t] - orig;   // exclusive block offsets
}

__global__ void k_scan_c(int* __restrict__ rowptr, int* __restrict__ cursor,
                         const int* __restrict__ partials, int n, int total)
{
  int i = blockIdx.x * blockDim.x + threadIdx.x;
  if (i == 0) rowptr[n] = total;
  if (i >= n) return;
  int r = rowptr[i] + partials[i >> 10];
  rowptr[i] = r;
  cursor[i] = r;
}

__global__ void k_scatter(const int* __restrict__ ei, const int* __restrict__ xv,
                          int* __restrict__ cursor, int* __restrict__ col,
                          ushort* __restrict__ colv, int E, int N)
{
  int e = blockIdx.x * blockDim.x + threadIdx.x;
  if (e >= E + N) return;
  int s, d;
  if (e < E) { s = ei[e]; d = ei[E + e]; } else { s = e - E; d = s; }
  int p = atomicAdd(&cursor[d], 1);
  col[p] = s;
  colv[p] = (ushort)xv[s];
}

// ===== fused layer-1: group(16 lanes) = one row; 4 rows per wave =============
// lane owns 8 channels (cb = l16*8); serial edge loop (x2 unrolled); no
// cross-group reductions; LN/dots via 4-step 16-wide shuffles.
__global__ void __launch_bounds__(256)
k_gath1(const int* __restrict__ rowptr, const ushort* __restrict__ colv,
        const int* __restrict__ xv,
        const float2* __restrict__ asv, const float2* __restrict__ adv,
        const ushort* __restrict__ embWb,
        const float* __restrict__ b1, const float* __restrict__ lng,
        const float* __restrict__ lnb,
        const float* __restrict__ was, const float* __restrict__ wad,
        ushort* __restrict__ g, float2* __restrict__ as2,
        float2* __restrict__ ad2, int N)
{
  int lane = threadIdx.x & 63;
  int wv = (blockIdx.x * blockDim.x + threadIdx.x) >> 6;
  int nw = (gridDim.x * blockDim.x) >> 6;
  int grp = lane >> 4, l16 = lane & 15;
  int headL = l16 >> 3;               // channels cb..cb+7 all in this head
  int cb = l16 * 8;
  float b1c[8], lngc[8], lnbc[8], was0[8], was1[8], wad0[8], wad1[8];
#pragma unroll
  for (int j = 0; j < 8; ++j) {
    b1c[j] = b1[cb + j]; lngc[j] = lng[cb + j]; lnbc[j] = lnb[cb + j];
    was0[j] = was[(cb + j) * 2]; was1[j] = was[(cb + j) * 2 + 1];
    wad0[j] = wad[(cb + j) * 2]; wad1[j] = wad[(cb + j) * 2 + 1];
  }
  for (int base = wv * 4; base < N; base += nw * 4) {
    int r = base + grp;
    bool valid = r < N;
    int start = 0, end = 0;
    float adh = 0.f;
    if (valid) {
      start = rowptr[r]; end = rowptr[r + 1];
      float2 ad = adv[xv[r]];
      adh = headL ? ad.y : ad.x;
    }
    float acc[8] = {0.f, 0.f, 0.f, 0.f, 0.f, 0.f, 0.f, 0.f};
    float s = 0.f;
    int p = start;
    for (; p + 1 < end; p += 2) {
      int i0 = colv[p], i1 = colv[p + 1];
      float2 a0 = asv[i0], a1 = asv[i1];
      u16x8 v0 = *(const u16x8*)&embWb[(size_t)i0 * H2C + cb];
      u16x8 v1 = *(const u16x8*)&embWb[(size_t)i1 * H2C + cb];
      float e0 = (headL ? a0.y : a0.x) + adh; e0 = e0 >= 0.f ? e0 : 0.2f * e0;
      float e1 = (headL ? a1.y : a1.x) + adh; e1 = e1 >= 0.f ? e1 : 0.2f * e1;
      float ex0 = __expf(e0), ex1 = __expf(e1);
      s += ex0 + ex1;
#pragma unroll
      for (int j = 0; j < 8; ++j)
        acc[j] += ex0 * bfu2f(v0[j]) + ex1 * bfu2f(v1[j]);
    }
    if (p < end) {
      int i0 = colv[p];
      float2 a0 = asv[i0];
      u16x8 v0 = *(const u16x8*)&embWb[(size_t)i0 * H2C + cb];
      float e0 = (headL ? a0.y : a0.x) + adh; e0 = e0 >= 0.f ? e0 : 0.2f * e0;
      float ex0 = __expf(e0);
      s += ex0;
#pragma unroll
      for (int j = 0; j < 8; ++j) acc[j] += ex0 * bfu2f(v0[j]);
    }
    float rr = __fdividef(1.f, s + 1e-16f);
    float x[8], sum = 0.f, ssq = 0.f;
#pragma unroll
    for (int j = 0; j < 8; ++j) {
      x[j] = acc[j] * rr + b1c[j];
      sum += x[j]; ssq += x[j] * x[j];
    }
#pragma unroll
    for (int off = 1; off < 16; off <<= 1) {
      sum += __shfl_xor(sum, off, 64);
      ssq += __shfl_xor(ssq, off, 64);
    }
    float mean = sum * (1.f / 128.f);
    float var  = ssq * (1.f / 128.f) - mean * mean;
    float rstd = rsqrtf(var + 1e-5f);
    float ps0 = 0.f, ps1 = 0.f, pd0 = 0.f, pd1 = 0.f;
    u16x8 gv;
#pragma unroll
    for (int j = 0; j < 8; ++j) {
      float t = (x[j] - mean) * rstd * lngc[j] + lnbc[j];
      t = 0.5f * t * (1.f + erf_fast(t * 0.70710678118654752f));
      gv[j] = f2bfu(t);
      ps0 += t * was0[j]; ps1 += t * was1[j];
      pd0 += t * wad0[j]; pd1 += t * wad1[j];
    }
#pragma unroll
    for (int off = 1; off < 16; off <<= 1) {
      ps0 += __shfl_xor(ps0, off, 64); ps1 += __shfl_xor(ps1, off, 64);
      pd0 += __shfl_xor(pd0, off, 64); pd1 += __shfl_xor(pd1, off, 64);
    }
    if (valid) {
      *(u16x8*)&g[(size_t)r * H2C + cb] = gv;
      if (l16 == 0) {
        as2[r] = make_float2(ps0, ps1);
        ad2[r] = make_float2(pd0, pd1);
      }
    }
  }
}

// ===== fused layer-2: group(16 lanes) = one row; 4 rows per wave =============
__global__ void __launch_bounds__(256)
k_gath2(const int* __restrict__ rowptr, const int* __restrict__ col,
        const float2* __restrict__ as2, const float2* __restrict__ ad2,
        const ushort* __restrict__ h2b, const float* __restrict__ b2,
        ushort* __restrict__ g2, int N)
{
  int lane = threadIdx.x & 63;
  int wv = (blockIdx.x * blockDim.x + threadIdx.x) >> 6;
  int nw = (gridDim.x * blockDim.x) >> 6;
  int grp = lane >> 4, l16 = lane & 15;
  int headL = l16 >> 3;
  int cb = l16 * 8;
  float b2c[8];
#pragma unroll
  for (int j = 0; j < 8; ++j) b2c[j] = b2[cb + j];
  for (int base = wv * 4; base < N; base += nw * 4) {
    int r = base + grp;
    bool valid = r < N;
    int start = 0, end = 0;
    float adh = 0.f;
    if (valid) {
      start = rowptr[r]; end = rowptr[r + 1];
      float2 ad = ad2[r];
      adh = headL ? ad.y : ad.x;
    }
    float acc[8] = {0.f, 0.f, 0.f, 0.f, 0.f, 0.f, 0.f, 0.f};
    float s = 0.f;
    int p = start;
    for (; p + 1 < end; p += 2) {
      int i0 = col[p], i1 = col[p + 1];
      float2 a0 = as2[i0], a1 = as2[i1];
      u16x8 v0 = *(const u16x8*)&h2b[(size_t)i0 * H2C + cb];
      u16x8 v1 = *(const u16x8*)&h2b[(size_t)i1 * H2C + cb];
      float e0 = (headL ? a0.y : a0.x) + adh; e0 = e0 >= 0.f ? e0 : 0.2f * e0;
      float e1 = (headL ? a1.y : a1.x) + adh; e1 = e1 >= 0.f ? e1 : 0.2f * e1;
      float ex0 = __expf(e0), ex1 = __expf(e1);
      s += ex0 + ex1;
#pragma unroll
      for (int j = 0; j < 8; ++j)
        acc[j] += ex0 * bfu2f(v0[j]) + ex1 * bfu2f(v1[j]);
    }
    if (p < end) {
      int i0 = col[p];
      float2 a0 = as2[i0];
      u16x8 v0 = *(const u16x8*)&h2b[(size_t)i0 * H2C + cb];
      float e0 = (headL ? a0.y : a0.x) + adh; e0 = e0 >= 0.f ? e0 : 0.2f * e0;
      float ex0 = __expf(e0);
      s += ex0;
#pragma unroll
      for (int j = 0; j < 8; ++j) acc[j] += ex0 * bfu2f(v0[j]);
    }
    float rr = __fdividef(1.f, s + 1e-16f);
    u16x8 gv;
#pragma unroll
    for (int j = 0; j < 8; ++j) gv[j] = f2bfu(acc[j] * rr + b2c[j]);
    if (valid) *(u16x8*)&g2[(size_t)r * H2C + cb] = gv;
  }
}

// ---------------- h2b = bf16(g @ W2) via bf16 MFMA ---------------------------
__global__ void __launch_bounds__(256) k_gemm(const ushort* __restrict__ g,
                                              const ushort* __restrict__ w2bt,
                                              ushort* __restrict__ h2b, int N)
{
  __shared__ ushort As[H2C * H2C];
  __shared__ ushort Bs[H2C * H2C];
  int tid = threadIdx.x, lane = tid & 63, wv = tid >> 6;
  size_t rbase = (size_t)blockIdx.x * 128;

#pragma unroll
  for (int it = 0; it < 8; ++it) {
    int cb = (it * 4 + wv) * 64;
    int chunk = cb + lane;
    int row = chunk >> 4, kc = chunk & 15;
    int sc = (row << 4) | (kc ^ (row & 7));
    __builtin_amdgcn_global_load_lds(
        (const __attribute__((address_space(1))) void*)(g + rbase * H2C + (size_t)sc * 8),
        (__attribute__((address_space(3))) void*)(As + cb * 8), 16, 0, 0);
    __builtin_amdgcn_global_load_lds(
        (const __attribute__((address_space(1))) void*)(w2bt + (size_t)sc * 8),
        (__attribute__((address_space(3))) void*)(Bs + cb * 8), 16, 0, 0);
  }
  __syncthreads();

  f32x4 acc[2][8];
#pragma unroll
  for (int i = 0; i < 2; ++i)
#pragma unroll
    for (int j = 0; j < 8; ++j) acc[i][j] = (f32x4)0.f;

  int r15 = lane & 15, kg = lane >> 4;
#pragma unroll
  for (int ks = 0; ks < 4; ++ks) {
    int kc = ks * 4 + kg;
    s16x8 af[2], bfr[8];
#pragma unroll
    for (int mr = 0; mr < 2; ++mr) {
      int row = wv * 32 + mr * 16 + r15;
      af[mr] = *(const s16x8*)&As[row * H2C + (kc ^ (row & 7)) * 8];
    }
#pragma unroll
    for (int cf = 0; cf < 8; ++cf) {
      int row = cf * 16 + r15;
      bfr[cf] = *(const s16x8*)&Bs[row * H2C + (kc ^ (row & 7)) * 8];
    }
#pragma unroll
    for (int mr = 0; mr < 2; ++mr)
#pragma unroll
      for (int cf = 0; cf < 8; ++cf)
        acc[mr][cf] = __builtin_amdgcn_mfma_f32_16x16x32_bf16(af[mr], bfr[cf], acc[mr][cf], 0, 0, 0);
  }

#pragma unroll
  for (int mr = 0; mr < 2; ++mr) {
    int row0 = (int)rbase + wv * 32 + mr * 16 + kg * 4;
#pragma unroll
    for (int r = 0; r < 4; ++r) {
      int row = row0 + r;
      if (row < N) {
#pragma unroll
        for (int cf = 0; cf < 8; ++cf)
          h2b[(size_t)row * H2C + cf * 16 + r15] = f2bfu(acc[mr][cf][r]);
      }
    }
  }
}

// ---------------- h3 = g2 @ Wp + bp via bf16 MFMA (128 -> 64) ----------------
__global__ void __launch_bounds__(256) k_gemmP(const ushort* __restrict__ g2,
                                               const ushort* __restrict__ wpbt,
                                               const float* __restrict__ bp,
                                               float* __restrict__ h3, int N)
{
  __shared__ ushort As[H2C * H2C];
  __shared__ ushort Bs[CDIM * H2C];
  int tid = threadIdx.x, lane = tid & 63, wv = tid >> 6;
  size_t rbase = (size_t)blockIdx.x * 128;

#pragma unroll
  for (int it = 0; it < 8; ++it) {
    int cb = (it * 4 + wv) * 64;
    int chunk = cb + lane;
    int row = chunk >> 4, kc = chunk & 15;
    int sc = (row << 4) | (kc ^ (row & 7));
    __builtin_amdgcn_global_load_lds(
        (const __attribute__((address_space(1))) void*)(g2 + rbase * H2C + (size_t)sc * 8),
        (__attribute__((address_space(3))) void*)(As + cb * 8), 16, 0, 0);
  }
#pragma unroll
  for (int it = 0; it < 4; ++it) {
    int cb = (it * 4 + wv) * 64;
    int chunk = cb + lane;
    int row = chunk >> 4, kc = chunk & 15;
    int sc = (row << 4) | (kc ^ (row & 7));
    __builtin_amdgcn_global_load_lds(
        (const __attribute__((address_space(1))) void*)(wpbt + (size_t)sc * 8),
        (__attribute__((address_space(3))) void*)(Bs + cb * 8), 16, 0, 0);
  }
  __syncthreads();

  f32x4 acc[2][4];
#pragma unroll
  for (int i = 0; i < 2; ++i)
#pragma unroll
    for (int j = 0; j < 4; ++j) acc[i][j] = (f32x4)0.f;

  int r15 = lane & 15, kg = lane >> 4;
#pragma unroll
  for (int ks = 0; ks < 4; ++ks) {
    int kc = ks * 4 + kg;
    s16x8 af[2], bfr[4];
#pragma unroll
    for (int mr = 0; mr < 2; ++mr) {
      int row = wv * 32 + mr * 16 + r15;
      af[mr] = *(const s16x8*)&As[row * H2C + (kc ^ (row & 7)) * 8];
    }
#pragma unroll
    for (int cf = 0; cf < 4; ++cf) {
      int row = cf * 16 + r15;
      bfr[cf] = *(const s16x8*)&Bs[row * H2C + (kc ^ (row & 7)) * 8];
    }
#pragma unroll
    for (int mr = 0; mr < 2; ++mr)
#pragma unroll
      for (int cf = 0; cf < 4; ++cf)
        acc[mr][cf] = __builtin_amdgcn_mfma_f32_16x16x32_bf16(af[mr], bfr[cf], acc[mr][cf], 0, 0, 0);
  }

#pragma unroll
  for (int mr = 0; mr < 2; ++mr) {
    int row0 = (int)rbase + wv * 32 + mr * 16 + kg * 4;
#pragma unroll
    for (int r = 0; r < 4; ++r) {
      int row = row0 + r;
      if (row < N) {
#pragma unroll
        for (int cf = 0; cf < 4; ++cf)
          h3[(size_t)row * CDIM + cf * 16 + r15] = acc[mr][cf][r] + bp[cf * 16 + r15];
      }
    }
  }
}

// ---------------- graph mean pool (batch_idx is sorted), 4 waves/graph -------
__global__ void __launch_bounds__(256)
k_pool(const float* __restrict__ h3, const int* __restrict__ bidx,
       float* __restrict__ z, int N)
{
  __shared__ float sh[4][64];
  int g = blockIdx.x;
  int lane = threadIdx.x & 63;
  int w = threadIdx.x >> 6;
  int lo = 0, hi = N;
  while (lo < hi) { int mid = (lo + hi) >> 1; if (bidx[mid] < g) lo = mid + 1; else hi = mid; }
  int s0 = lo;
  hi = N;
  while (lo < hi) { int mid = (lo + hi) >> 1; if (bidx[mid] < g + 1) lo = mid + 1; else hi = mid; }
  int s1 = lo;
  float sum = 0.f;
  for (int i = s0 + w; i < s1; i += 4) sum += h3[(size_t)i * CDIM + lane];
  sh[w][lane] = sum;
  __syncthreads();
  if (w == 0) {
    sum = sh[0][lane] + sh[1][lane] + sh[2][lane] + sh[3][lane];
    z[g * CDIM + lane] = sum / fmaxf((float)(s1 - s0), 1.f);
  }
}

extern "C" void kernel_launch(void* const* d_in, const int* in_sizes, int n_in,
                              void* d_out, int out_size, void* d_ws, size_t ws_size,
                              hipStream_t stream)
{
  const int*   xv   = (const int*)d_in[0];
  const int*   ei   = (const int*)d_in[1];
  const int*   bidx = (const int*)d_in[2];
  const float* emb  = (const float*)d_in[3];
  const float* W1   = (const float*)d_in[4];
  const float* as1  = (const float*)d_in[5];
  const float* ad1  = (const float*)d_in[6];
  const float* b1   = (const float*)d_in[7];
  const float* lng  = (const float*)d_in[8];
  const float* lnb  = (const float*)d_in[9];
  const float* W2   = (const float*)d_in[10];
  const float* as2w = (const float*)d_in[11];
  const float* ad2w = (const float*)d_in[12];
  const float* b2   = (const float*)d_in[13];
  const float* Wp   = (const float*)d_in[14];
  const float* bp   = (const float*)d_in[15];

  const int N   = in_sizes[2];
  const int E   = in_sizes[1] / 2;
  const int V   = in_sizes[3] / CDIM;
  const int NG  = (out_size - N * CDIM) / CDIM;
  const int TOT = E + N;
  const int NB  = (N + 127) / 128;          // GEMM row tiles
  const size_t NPAD = (size_t)NB * 128;     // bf16 matrices readable up to here

  size_t off = 0;
  auto alloc = [&](size_t bytes) -> void* {
    void* p = (char*)d_ws + off;
    off += (bytes + 255) & ~(size_t)255;
    return p;
  };
  ushort* embWb  = (ushort*)alloc((size_t)V * H2C * 2);
  float*  asv    = (float*)alloc((size_t)V * 2 * 4);
  float*  adv    = (float*)alloc((size_t)V * 2 * 4);
  ushort* w2bt   = (ushort*)alloc((size_t)H2C * H2C * 2);
  ushort* wpbt   = (ushort*)alloc((size_t)CDIM * H2C * 2);
  float*  was    = (float*)alloc((size_t)H2C * 2 * 4);
  float*  wad    = (float*)alloc((size_t)H2C * 2 * 4);
  ushort* g      = (ushort*)alloc(NPAD * H2C * 2);
  ushort* h2b    = (ushort*)alloc((size_t)N * H2C * 2);
  ushort* g2     = (ushort*)alloc(NPAD * H2C * 2);
  float2* as2    = (float2*)alloc((size_t)N * 8);
  float2* ad2    = (float2*)alloc((size_t)N * 8);
  int*    deg    = (int*)alloc((size_t)N * 4);
  int*    rowptr = (int*)alloc(((size_t)N + 1) * 4);
  int*    cursor = (int*)alloc((size_t)N * 4);
  int*    col    = (int*)alloc((size_t)TOT * 4);
  ushort* colv   = (ushort*)alloc((size_t)TOT * 2);
  int*    partials = (int*)alloc(512 * 4);
  (void)ws_size; (void)n_in;

  hipMemsetAsync(deg, 0, (size_t)N * 4, stream);
  k_embw<<<V, 128, 0, stream>>>(emb, W1, as1, ad1, embWb, asv, adv);
  k_w2prep<<<H2C, H2C, 0, stream>>>(W2, as2w, ad2w, w2bt, was, wad);
  k_wpprep<<<H2C, CDIM, 0, stream>>>(Wp, wpbt);
  int nbE = (TOT + 255) / 256;
  k_deg<<<nbE, 256, 0, stream>>>(ei, deg, E, N);
  int nbS = (N + 1023) / 1024;
  k_scan_a<<<nbS, 256, 0, stream>>>(deg, rowptr, partials, N);
  k_scan_b<<<1, 512, 0, stream>>>(partials, nbS);
  k_scan_c<<<(N + 255) / 256, 256, 0, stream>>>(rowptr, cursor, partials, N, TOT);
  k_scatter<<<nbE, 256, 0, stream>>>(ei, xv, cursor, col, colv, E, N);
  // layer 1 (group-per-row softmax-gather + LN + GELU + dots)
  k_gath1<<<2048, 256, 0, stream>>>(rowptr, colv, xv, (const float2*)asv,
                                    (const float2*)adv, embWb, b1, lng, lnb,
                                    was, wad, g, as2, ad2, N);
  k_gemm<<<NB, 256, 0, stream>>>(g, w2bt, h2b, N);
  // layer 2 (group-per-row softmax-gather + bias)
  k_gath2<<<2048, 256, 0, stream>>>(rowptr, col, as2, ad2, h2b, b2, g2, N);
  float* outh = (float*)d_out;
  k_gemmP<<<NB, 256, 0, stream>>>(g2, wpbt, bp, outh, N);
  k_pool<<<NG, 256, 0, stream>>>(outh, bidx, outh + (size_t)N * CDIM, N);
}